// Round 9
// baseline (412.559 us; speedup 1.0000x reference)
//
#include <hip/hip_runtime.h>

#define DIM 128
#define BN_EPS 1e-5f
#define STAT_COPIES 64

typedef short short8 __attribute__((ext_vector_type(8)));   // 8 bf16 bit patterns
typedef float floatx4 __attribute__((ext_vector_type(4)));

__device__ __forceinline__ unsigned short f2bf(float f) {
    unsigned int u = __builtin_bit_cast(unsigned int, f);
    u += 0x7FFFu + ((u >> 16) & 1u);          // RNE (inputs are finite)
    return (unsigned short)(u >> 16);
}
__device__ __forceinline__ float bf2f(unsigned short h) {
    return __builtin_bit_cast(float, (unsigned int)h << 16);
}

// ---------------- K1: degree (atomic, rank captured) + W1->bf16 conversion -----
// rank[e] = edge's arrival index within its row bucket (free from atomicAdd
// return) -> scatter needs no second atomic pass. Only W1 fragments needed now
// (layer-2 GEMM runs fp32 from the original W2).
// wfrag[((kt*8+nt)*64 + lane)*8 + j] = W1[kt*32 + (lane>>4)*8 + j][nt*16 + (lane&15)]

__global__ __launch_bounds__(256) void deg_convw_kernel(
    const int* __restrict__ row, int* __restrict__ deg, int* __restrict__ rank,
    int E, int degB,
    const float* __restrict__ W1, unsigned short* __restrict__ wfrag)
{
    if ((int)blockIdx.x < degB) {
        int e = blockIdx.x * 256 + threadIdx.x;
        if (e < E) rank[e] = atomicAdd(&deg[row[e]], 1);
    } else {
        int s = (blockIdx.x - degB) * 256 + threadIdx.x;   // 0..2047
        if (s >= 2048) return;
        int kt = s >> 9;
        int nt = (s >> 6) & 7;
        int l  = s & 63;
        unsigned short* o = wfrag + (size_t)s * 8;
        int k0 = kt * 32 + (l >> 4) * 8;
        int n0 = nt * 16 + (l & 15);
        #pragma unroll
        for (int j = 0; j < 8; ++j) o[j] = f2bf(W1[(k0 + j) * DIM + n0]);
    }
}

// ---------------- K2: per-block exclusive scan over deg (+ fused dis) ----------

__global__ __launch_bounds__(256) void scan_block_kernel(const int* __restrict__ deg,
                                                         int* __restrict__ rowptr,
                                                         int* __restrict__ aux,
                                                         float* __restrict__ dis, int n) {
    __shared__ int ls[256];
    const int base = blockIdx.x * 1024;
    const int t = threadIdx.x;
    int v[4]; int s = 0;
    #pragma unroll
    for (int k = 0; k < 4; ++k) {
        int i = base + t * 4 + k;
        v[k] = (i < n) ? deg[i] : 0;
        s += v[k];
    }
    ls[t] = s;
    __syncthreads();
    for (int off = 1; off < 256; off <<= 1) {
        int x = (t >= off) ? ls[t - off] : 0;
        __syncthreads();
        ls[t] += x;
        __syncthreads();
    }
    int excl = ls[t] - s;
    if (t == 255) aux[blockIdx.x] = ls[255];
    #pragma unroll
    for (int k = 0; k < 4; ++k) {
        int i = base + t * 4 + k;
        if (i < n) {
            rowptr[i] = excl;
            dis[i] = rsqrtf((float)(v[k] + 1));   // +1 self-loop; always > 0
        }
        excl += v[k];
    }
}

// ---------------- K3: add aux prefix (computed per-block), build rp2 ----------

__global__ __launch_bounds__(256) void add_offsets_kernel(
    const int* __restrict__ rowptr, const int* __restrict__ deg,
    const int* __restrict__ aux, int2* __restrict__ rp2, int n)
{
    __shared__ int red[256];
    const int t = threadIdx.x;
    red[t] = (t < (int)blockIdx.x) ? aux[t] : 0;   // blockIdx <= 255 by construction
    __syncthreads();
    for (int off = 128; off > 0; off >>= 1) {
        if (t < off) red[t] += red[t + off];
        __syncthreads();
    }
    const int base = red[0];
    #pragma unroll
    for (int k = 0; k < 4; ++k) {
        int i = blockIdx.x * 1024 + t * 4 + k;
        if (i < n) {
            int st = rowptr[i] + base;
            rp2[i] = make_int2(st, st + deg[i]);
        }
    }
}

// ---------------- K4: scatter (atomic-free) INTERLEAVED with MFMA GEMM layer 1 --
// mod-5 block mapping: 3 scatter : 2 gemm so every CU holds a mix from t=0.
// GEMM: direct fragment loads from global (A used once), no LDS, no barrier.

__global__ __launch_bounds__(256) void scatter_gemm1_kernel(
    const int* __restrict__ row, const int* __restrict__ col,
    const int* __restrict__ rank, const float* __restrict__ dis,
    const int2* __restrict__ rp2, int2* __restrict__ epack, int E, int scatS,
    const float* __restrict__ A, const unsigned short* __restrict__ wfrag,
    unsigned short* __restrict__ C, int n, int gemmG)
{
    const int grp = blockIdx.x / 5;
    const int off = blockIdx.x % 5;
    if (off < 3) {
        const int sId = grp * 3 + off;
        if (sId >= scatS) return;
        int e = sId * 256 + threadIdx.x;
        if (e >= E) return;
        int r = row[e], c = col[e];
        int pos = rp2[r].x + rank[e];
        float nrm = dis[r] * dis[c];
        epack[pos] = make_int2(c, __builtin_bit_cast(int, nrm));
    } else {
        const int gId = grp * 2 + (off - 3);
        if (gId >= gemmG) return;
        const int tid  = threadIdx.x;
        const int row0 = gId * 64;
        const int wave = tid >> 6;
        const int lane = tid & 63;
        const int m    = lane & 15;
        const int quad = lane >> 4;
        const int rowA = row0 + wave * 16 + m;

        short8 af[4];
        if (rowA < n) {
            #pragma unroll
            for (int kt = 0; kt < 4; ++kt) {
                const float* src = A + (size_t)rowA * DIM + kt * 32 + quad * 8;
                float4 v0 = *(const float4*)(src);
                float4 v1 = *(const float4*)(src + 4);
                af[kt] = (short8){ (short)f2bf(v0.x), (short)f2bf(v0.y),
                                   (short)f2bf(v0.z), (short)f2bf(v0.w),
                                   (short)f2bf(v1.x), (short)f2bf(v1.y),
                                   (short)f2bf(v1.z), (short)f2bf(v1.w) };
            }
        } else {
            #pragma unroll
            for (int kt = 0; kt < 4; ++kt) af[kt] = (short8){0,0,0,0,0,0,0,0};
        }

        floatx4 acc[8];
        #pragma unroll
        for (int nt = 0; nt < 8; ++nt) acc[nt] = (floatx4){0.f, 0.f, 0.f, 0.f};

        #pragma unroll
        for (int nt = 0; nt < 8; ++nt)
            #pragma unroll
            for (int kt = 0; kt < 4; ++kt) {
                short8 bfr = *(const short8*)(wfrag + ((size_t)(kt * 8 + nt) * 64 + lane) * 8);
                acc[nt] = __builtin_amdgcn_mfma_f32_16x16x32_bf16(af[kt], bfr, acc[nt], 0, 0, 0);
            }

        #pragma unroll
        for (int nt = 0; nt < 8; ++nt)
            #pragma unroll
            for (int r = 0; r < 4; ++r) {
                int rr = row0 + wave * 16 + quad * 4 + r;
                if (rr < n) C[(size_t)rr * DIM + nt * 16 + m] = f2bf(acc[nt][r]);
            }
    }
}

// ---------------- K5: CSR aggregation layer 1 (+ fused BN stats) ----------------
// 16 lanes/node, 8 ch/lane. h1[i] = sum_e hw[col_e]*norm_e + hw[i]*dis_i^2 + b1.
// Uniform predicated unroll-8 loop: index clamped to pe-1, weight 0 for pad slots.
// STATS: LDS reduce + atomics over 64 spread copies; no fence (round-3 lesson).

__device__ __forceinline__ void acc8(float* acc, uint4 u, float w) {
    unsigned int a[4] = {u.x, u.y, u.z, u.w};
    #pragma unroll
    for (int k = 0; k < 4; ++k) {
        acc[2*k]   = fmaf(bf2f((unsigned short)(a[k] & 0xffff)), w, acc[2*k]);
        acc[2*k+1] = fmaf(bf2f((unsigned short)(a[k] >> 16)),    w, acc[2*k+1]);
    }
}

__global__ __launch_bounds__(256) void agg1_kernel(
    const unsigned short* __restrict__ hw, const float* __restrict__ dis,
    const int2* __restrict__ rp2, const int2* __restrict__ epack,
    const float* __restrict__ bias, unsigned short* __restrict__ out, int n,
    float* __restrict__ stat)
{
    const int sub  = threadIdx.x >> 4;        // 0..15 node slot in block
    const int l    = threadIdx.x & 15;
    const int node = blockIdx.x * 16 + sub;
    const bool valid = node < n;
    const int j = l * 8;

    float acc[8];
    #pragma unroll
    for (int k = 0; k < 8; ++k) acc[k] = 0.f;

    if (valid) {
        const int2 rp = rp2[node];            // one 8B load: {start, end}
        {   // self-loop term: hw[i] * dis_i^2
            const float d = dis[node];
            uint4 u = *(const uint4*)(hw + (size_t)node * DIM + j);
            acc8(acc, u, d * d);
        }

        const int pe = rp.y;
        for (int p = rp.x; p < pe; p += 8) {
            const int pm = pe - 1;
            int2 e[8];
            #pragma unroll
            for (int k = 0; k < 8; ++k) {
                int pk = p + k;
                e[k] = epack[pk < pm ? pk : pm];
            }
            uint4 u[8];
            #pragma unroll
            for (int k = 0; k < 8; ++k)
                u[k] = *(const uint4*)(hw + (size_t)e[k].x * DIM + j);
            #pragma unroll
            for (int k = 0; k < 8; ++k) {
                float w = (p + k < pe) ? __builtin_bit_cast(float, e[k].y) : 0.f;
                acc8(acc, u[k], w);
            }
        }

        float4 b0 = *(const float4*)(bias + j);
        float4 b1 = *(const float4*)(bias + j + 4);
        acc[0] += b0.x; acc[1] += b0.y; acc[2] += b0.z; acc[3] += b0.w;
        acc[4] += b1.x; acc[5] += b1.y; acc[6] += b1.z; acc[7] += b1.w;

        uint4 o;
        o.x = (unsigned int)f2bf(acc[0]) | ((unsigned int)f2bf(acc[1]) << 16);
        o.y = (unsigned int)f2bf(acc[2]) | ((unsigned int)f2bf(acc[3]) << 16);
        o.z = (unsigned int)f2bf(acc[4]) | ((unsigned int)f2bf(acc[5]) << 16);
        o.w = (unsigned int)f2bf(acc[6]) | ((unsigned int)f2bf(acc[7]) << 16);
        *(uint4*)(out + (size_t)node * DIM + j) = o;
    }

    // BN stats: row padded to 257 floats (4-way write conflicts max).
    __shared__ float red[16][257];
    #pragma unroll
    for (int k = 0; k < 8; ++k) {
        float a = valid ? acc[k] : 0.f;
        red[sub][j + k]       = a;
        red[sub][128 + j + k] = a * a;
    }
    __syncthreads();
    float t = 0.f;
    #pragma unroll
    for (int r = 0; r < 16; ++r) t += red[r][threadIdx.x];
    atomicAdd(&stat[(blockIdx.x & (STAT_COPIES - 1)) * 256 + threadIdx.x], t);
}

// ---------------- BN finalize: fold stats into scale/shift ----------------

__global__ void bn_finalize_kernel(const float* __restrict__ stat,
                                   const float* __restrict__ gamma,
                                   const float* __restrict__ beta,
                                   float* __restrict__ mi, int n) {
    int c = threadIdx.x;
    if (c < DIM) {
        float s = 0.f, q = 0.f;
        #pragma unroll 4
        for (int cp = 0; cp < STAT_COPIES; ++cp) {
            s += stat[cp * 256 + c];
            q += stat[cp * 256 + 128 + c];
        }
        float mean  = s / (float)n;
        float var   = q / (float)n - mean * mean;
        float istd  = rsqrtf(var + BN_EPS);
        float scale = gamma[c] * istd;
        mi[c]       = scale;
        mi[DIM + c] = fmaf(-mean, scale, beta[c]);   // shift
    }
}

// ---------------- K7: fused agg2 + GEMM2 (fp32 phase 2) ----------------
// Associativity: out = A_hat·(Z·W2)+b2 = (A_hat·Z)·W2+b2 with Z=relu(BN(h1)).
// Phase 1 (gather): S[node] = sum_e Z[col_e]*norm_e + Z[node]*dis^2 in fp32.
// Phase 2: rounds 7/8 lesson — ANY bf16 representation of this path's operands
// fails (0.29 single-bf16, 0.23 hi/lo+bf16 W2). Phase 2 is tiny (16x128x128 =
// 262k MAC/block, ~21us of VALU chip-wide, hidden under gather latency at 6%
// VALUBusy) -> do it in fp32 VALU with the ORIGINAL fp32 W2 (64KB, L2-resident).
// Only roundings left: bf16 hw and bf16 h1 — same as the verified split path.

__global__ __launch_bounds__(256) void agg2_gemm_kernel(
    const unsigned short* __restrict__ h1, const float* __restrict__ dis,
    const int2* __restrict__ rp2, const int2* __restrict__ epack,
    const float* __restrict__ W2,               // fp32, row-major [128][128]
    const float* __restrict__ mi,               // [0..127]=scale, [128..255]=shift
    const float* __restrict__ b2,
    float* __restrict__ out, int n)
{
    __shared__ float sSf[16][132];
    const int tid  = threadIdx.x;
    const int sub  = tid >> 4;
    const int l    = tid & 15;
    const int node0 = blockIdx.x * 16;
    const int node = node0 + sub;
    const bool valid = node < n;
    const int j = l * 8;

    float sc[8], sh[8];
    #pragma unroll
    for (int k = 0; k < 8; ++k) { sc[k] = mi[j + k]; sh[k] = mi[128 + j + k]; }

    float acc[8];
    #pragma unroll
    for (int k = 0; k < 8; ++k) acc[k] = 0.f;

    if (valid) {
        const int2 rp = rp2[node];
        {   // self-loop: Z[node] * dis^2
            const float d = dis[node];
            const float dd = d * d;
            uint4 u = *(const uint4*)(h1 + (size_t)node * DIM + j);
            unsigned int a[4] = {u.x, u.y, u.z, u.w};
            #pragma unroll
            for (int k = 0; k < 4; ++k) {
                float z0 = fmaxf(fmaf(bf2f((unsigned short)(a[k] & 0xffff)), sc[2*k],   sh[2*k]),   0.f);
                float z1 = fmaxf(fmaf(bf2f((unsigned short)(a[k] >> 16)),    sc[2*k+1], sh[2*k+1]), 0.f);
                acc[2*k]   = fmaf(z0, dd, acc[2*k]);
                acc[2*k+1] = fmaf(z1, dd, acc[2*k+1]);
            }
        }

        const int pe = rp.y;
        for (int p = rp.x; p < pe; p += 8) {
            const int pm = pe - 1;
            int2 e[8];
            #pragma unroll
            for (int k = 0; k < 8; ++k) {
                int pk = p + k;
                e[k] = epack[pk < pm ? pk : pm];
            }
            uint4 u[8];
            #pragma unroll
            for (int k = 0; k < 8; ++k)
                u[k] = *(const uint4*)(h1 + (size_t)e[k].x * DIM + j);
            #pragma unroll
            for (int k = 0; k < 8; ++k) {
                float w = (p + k < pe) ? __builtin_bit_cast(float, e[k].y) : 0.f;
                unsigned int a[4] = {u[k].x, u[k].y, u[k].z, u[k].w};
                #pragma unroll
                for (int q = 0; q < 4; ++q) {
                    float z0 = fmaxf(fmaf(bf2f((unsigned short)(a[q] & 0xffff)), sc[2*q],   sh[2*q]),   0.f);
                    float z1 = fmaxf(fmaf(bf2f((unsigned short)(a[q] >> 16)),    sc[2*q+1], sh[2*q+1]), 0.f);
                    acc[2*q]   = fmaf(z0, w, acc[2*q]);
                    acc[2*q+1] = fmaf(z1, w, acc[2*q+1]);
                }
            }
        }
    }

    // stage fp32 S tile (invalid rows = 0; 2-way bank aliasing only)
    *(float4*)(&sSf[sub][j])     = make_float4(acc[0], acc[1], acc[2], acc[3]);
    *(float4*)(&sSf[sub][j + 4]) = make_float4(acc[4], acc[5], acc[6], acc[7]);
    __syncthreads();

    // Phase 2 (fp32 VALU): out[node][j..j+7] = S[node][:] @ W2[:][j..j+7] + b2
    float4 bb0 = *(const float4*)(b2 + j);
    float4 bb1 = *(const float4*)(b2 + j + 4);
    float o[8] = { bb0.x, bb0.y, bb0.z, bb0.w, bb1.x, bb1.y, bb1.z, bb1.w };
    #pragma unroll 4
    for (int k = 0; k < DIM; ++k) {
        float sv = sSf[sub][k];                          // broadcast across 16 lanes
        float4 w0 = *(const float4*)(W2 + (size_t)k * DIM + j);
        float4 w1 = *(const float4*)(W2 + (size_t)k * DIM + j + 4);
        o[0] = fmaf(sv, w0.x, o[0]);
        o[1] = fmaf(sv, w0.y, o[1]);
        o[2] = fmaf(sv, w0.z, o[2]);
        o[3] = fmaf(sv, w0.w, o[3]);
        o[4] = fmaf(sv, w1.x, o[4]);
        o[5] = fmaf(sv, w1.y, o[5]);
        o[6] = fmaf(sv, w1.z, o[6]);
        o[7] = fmaf(sv, w1.w, o[7]);
    }

    if (valid) {
        *(float4*)(out + (size_t)node * DIM + j)     = make_float4(o[0], o[1], o[2], o[3]);
        *(float4*)(out + (size_t)node * DIM + j + 4) = make_float4(o[4], o[5], o[6], o[7]);
    }
}

// ---------------- launch ----------------

extern "C" void kernel_launch(void* const* d_in, const int* in_sizes, int n_in,
                              void* d_out, int out_size, void* d_ws, size_t ws_size,
                              hipStream_t stream)
{
    const float* x      = (const float*)d_in[0];
    const int*   ei     = (const int*)  d_in[1];
    const float* W1     = (const float*)d_in[2];
    const float* b1     = (const float*)d_in[3];
    const float* gamma1 = (const float*)d_in[4];
    const float* beta1  = (const float*)d_in[5];
    const float* W2     = (const float*)d_in[6];
    const float* b2     = (const float*)d_in[7];
    float* out = (float*)d_out;

    const int N = in_sizes[0] / DIM;   // 100000
    const int E = in_sizes[1] / 2;     // 600000
    const int* row = ei;
    const int* col = ei + E;

    const int NB    = (N + 1023) / 1024;   // <= 256 (N <= 262144)
    const int degB  = (E + 255) / 256;
    const int gemmB = (N + 63) / 64;
    const int aggB  = (N + 15) / 16;
    // interleaved K4 grid: groups of 5 = 3 scatter + 2 gemm
    const int k4B   = 5 * max((degB + 2) / 3, (gemmB + 1) / 2);

    // Workspace layout (8B-alignment-safe ordering). Zeroed region is contiguous:
    unsigned short* hw    = (unsigned short*)d_ws;         // N*128 bf16
    unsigned short* h1    = hw + (size_t)N * DIM;          // N*128 bf16
    int2*  epack  = (int2*)(h1 + (size_t)N * DIM);         // E (8B each)
    int2*  rp2    = epack + E;                             // N {start,end}
    unsigned short* wfrag = (unsigned short*)(rp2 + N);    // 16384 bf16 (W1 frags)
    float* dis    = (float*)(wfrag + 2 * 16384);           // N
    int*   rank   = (int*)(dis + N);                       // E (edge rank in bucket)
    int*   rowptr = rank + E;                              // N (scratch, per-block scan)
    int*   aux    = rowptr + N;                            // 256
    float* mi     = (float*)(aux + 256);                   // 256
    // ---- zeroed region start ----
    int*   deg    = (int*)(mi + 256);                      // N
    float* stat   = (float*)(deg + N);                     // 64*256
    const size_t zero_bytes = (size_t)N * 4 + (size_t)STAT_COPIES * 256 * 4;

    hipMemsetAsync(deg, 0, zero_bytes, stream);

    // K1: degree atomics (rank captured) + W1 fragment conversion
    deg_convw_kernel<<<degB + 8, 256, 0, stream>>>(row, deg, rank, E, degB, W1, wfrag);
    // K2: per-block exclusive scan (+ dis)
    scan_block_kernel<<<NB, 256, 0, stream>>>(deg, rowptr, aux, dis, N);
    // K3: cross-block offsets (self-computed aux prefix) -> rp2
    add_offsets_kernel<<<NB, 256, 0, stream>>>(rowptr, deg, aux, rp2, N);
    // K4: atomic-free scatter interleaved (mod-5) with LDS-free gemm1
    scatter_gemm1_kernel<<<k4B, 256, 0, stream>>>(row, col, rank, dis, rp2, epack, E, degB,
                                                  x, wfrag, hw, N, gemmB);
    // K5: agg layer 1 + fused BN stats (spread atomics, no fence)
    agg1_kernel<<<aggB, 256, 0, stream>>>(hw, dis, rp2, epack, b1, h1, N, stat);
    // K5b: fold stats -> BN scale/shift (1 tiny block; kernel boundary = coherence)
    bn_finalize_kernel<<<1, DIM, 0, stream>>>(stat, gamma1, beta1, mi, N);
    // K7: fused agg2+gemm2 (fp32 phase 2): S = A_hat·relu(BN(h1)); out = S@W2 + b2
    agg2_gemm_kernel<<<aggB, 256, 0, stream>>>(h1, dis, rp2, epack, W2, mi, b2, out, N);
}

// Round 10
// 287.038 us; speedup vs baseline: 1.4373x; 1.4373x over previous
//
#include <hip/hip_runtime.h>

#define DIM 128
#define BN_EPS 1e-5f
#define STAT_COPIES 64

typedef short short8 __attribute__((ext_vector_type(8)));   // 8 bf16 bit patterns
typedef float floatx4 __attribute__((ext_vector_type(4)));

__device__ __forceinline__ unsigned short f2bf(float f) {
    unsigned int u = __builtin_bit_cast(unsigned int, f);
    u += 0x7FFFu + ((u >> 16) & 1u);          // RNE (inputs are finite)
    return (unsigned short)(u >> 16);
}
__device__ __forceinline__ float bf2f(unsigned short h) {
    return __builtin_bit_cast(float, (unsigned int)h << 16);
}

// ---------------- K1: degree (atomic, rank captured) + W1->bf16 conversion -----

__global__ __launch_bounds__(256) void deg_convw_kernel(
    const int* __restrict__ row, int* __restrict__ deg, int* __restrict__ rank,
    int E, int degB,
    const float* __restrict__ W1, unsigned short* __restrict__ wfrag)
{
    if ((int)blockIdx.x < degB) {
        int e = blockIdx.x * 256 + threadIdx.x;
        if (e < E) rank[e] = atomicAdd(&deg[row[e]], 1);
    } else {
        int s = (blockIdx.x - degB) * 256 + threadIdx.x;   // 0..2047
        if (s >= 2048) return;
        int kt = s >> 9;
        int nt = (s >> 6) & 7;
        int l  = s & 63;
        unsigned short* o = wfrag + (size_t)s * 8;
        int k0 = kt * 32 + (l >> 4) * 8;
        int n0 = nt * 16 + (l & 15);
        #pragma unroll
        for (int j = 0; j < 8; ++j) o[j] = f2bf(W1[(k0 + j) * DIM + n0]);
    }
}

// ---------------- K2: per-block exclusive scan over deg (+ fused dis) ----------

__global__ __launch_bounds__(256) void scan_block_kernel(const int* __restrict__ deg,
                                                         int* __restrict__ rowptr,
                                                         int* __restrict__ aux,
                                                         float* __restrict__ dis, int n) {
    __shared__ int ls[256];
    const int base = blockIdx.x * 1024;
    const int t = threadIdx.x;
    int v[4]; int s = 0;
    #pragma unroll
    for (int k = 0; k < 4; ++k) {
        int i = base + t * 4 + k;
        v[k] = (i < n) ? deg[i] : 0;
        s += v[k];
    }
    ls[t] = s;
    __syncthreads();
    for (int off = 1; off < 256; off <<= 1) {
        int x = (t >= off) ? ls[t - off] : 0;
        __syncthreads();
        ls[t] += x;
        __syncthreads();
    }
    int excl = ls[t] - s;
    if (t == 255) aux[blockIdx.x] = ls[255];
    #pragma unroll
    for (int k = 0; k < 4; ++k) {
        int i = base + t * 4 + k;
        if (i < n) {
            rowptr[i] = excl;
            dis[i] = rsqrtf((float)(v[k] + 1));   // +1 self-loop; always > 0
        }
        excl += v[k];
    }
}

// ---------------- K3: add aux prefix (computed per-block), build rp2 ----------

__global__ __launch_bounds__(256) void add_offsets_kernel(
    const int* __restrict__ rowptr, const int* __restrict__ deg,
    const int* __restrict__ aux, int2* __restrict__ rp2, int n)
{
    __shared__ int red[256];
    const int t = threadIdx.x;
    red[t] = (t < (int)blockIdx.x) ? aux[t] : 0;   // blockIdx <= 255 by construction
    __syncthreads();
    for (int off = 128; off > 0; off >>= 1) {
        if (t < off) red[t] += red[t + off];
        __syncthreads();
    }
    const int base = red[0];
    #pragma unroll
    for (int k = 0; k < 4; ++k) {
        int i = blockIdx.x * 1024 + t * 4 + k;
        if (i < n) {
            int st = rowptr[i] + base;
            rp2[i] = make_int2(st, st + deg[i]);
        }
    }
}

// ---------------- K4: scatter (atomic-free) INTERLEAVED with MFMA GEMM layer 1 --

__global__ __launch_bounds__(256) void scatter_gemm1_kernel(
    const int* __restrict__ row, const int* __restrict__ col,
    const int* __restrict__ rank, const float* __restrict__ dis,
    const int2* __restrict__ rp2, int2* __restrict__ epack, int E, int scatS,
    const float* __restrict__ A, const unsigned short* __restrict__ wfrag,
    unsigned short* __restrict__ C, int n, int gemmG)
{
    const int grp = blockIdx.x / 5;
    const int off = blockIdx.x % 5;
    if (off < 3) {
        const int sId = grp * 3 + off;
        if (sId >= scatS) return;
        int e = sId * 256 + threadIdx.x;
        if (e >= E) return;
        int r = row[e], c = col[e];
        int pos = rp2[r].x + rank[e];
        float nrm = dis[r] * dis[c];
        epack[pos] = make_int2(c, __builtin_bit_cast(int, nrm));
    } else {
        const int gId = grp * 2 + (off - 3);
        if (gId >= gemmG) return;
        const int tid  = threadIdx.x;
        const int row0 = gId * 64;
        const int wave = tid >> 6;
        const int lane = tid & 63;
        const int m    = lane & 15;
        const int quad = lane >> 4;
        const int rowA = row0 + wave * 16 + m;

        short8 af[4];
        if (rowA < n) {
            #pragma unroll
            for (int kt = 0; kt < 4; ++kt) {
                const float* src = A + (size_t)rowA * DIM + kt * 32 + quad * 8;
                float4 v0 = *(const float4*)(src);
                float4 v1 = *(const float4*)(src + 4);
                af[kt] = (short8){ (short)f2bf(v0.x), (short)f2bf(v0.y),
                                   (short)f2bf(v0.z), (short)f2bf(v0.w),
                                   (short)f2bf(v1.x), (short)f2bf(v1.y),
                                   (short)f2bf(v1.z), (short)f2bf(v1.w) };
            }
        } else {
            #pragma unroll
            for (int kt = 0; kt < 4; ++kt) af[kt] = (short8){0,0,0,0,0,0,0,0};
        }

        floatx4 acc[8];
        #pragma unroll
        for (int nt = 0; nt < 8; ++nt) acc[nt] = (floatx4){0.f, 0.f, 0.f, 0.f};

        #pragma unroll
        for (int nt = 0; nt < 8; ++nt)
            #pragma unroll
            for (int kt = 0; kt < 4; ++kt) {
                short8 bfr = *(const short8*)(wfrag + ((size_t)(kt * 8 + nt) * 64 + lane) * 8);
                acc[nt] = __builtin_amdgcn_mfma_f32_16x16x32_bf16(af[kt], bfr, acc[nt], 0, 0, 0);
            }

        #pragma unroll
        for (int nt = 0; nt < 8; ++nt)
            #pragma unroll
            for (int r = 0; r < 4; ++r) {
                int rr = row0 + wave * 16 + quad * 4 + r;
                if (rr < n) C[(size_t)rr * DIM + nt * 16 + m] = f2bf(acc[nt][r]);
            }
    }
}

// ---------------- K5: CSR aggregation layer 1 (+ fused BN stats) ----------------

__device__ __forceinline__ void acc8(float* acc, uint4 u, float w) {
    unsigned int a[4] = {u.x, u.y, u.z, u.w};
    #pragma unroll
    for (int k = 0; k < 4; ++k) {
        acc[2*k]   = fmaf(bf2f((unsigned short)(a[k] & 0xffff)), w, acc[2*k]);
        acc[2*k+1] = fmaf(bf2f((unsigned short)(a[k] >> 16)),    w, acc[2*k+1]);
    }
}

__global__ __launch_bounds__(256) void agg1_kernel(
    const unsigned short* __restrict__ hw, const float* __restrict__ dis,
    const int2* __restrict__ rp2, const int2* __restrict__ epack,
    const float* __restrict__ bias, unsigned short* __restrict__ out, int n,
    float* __restrict__ stat)
{
    const int sub  = threadIdx.x >> 4;        // 0..15 node slot in block
    const int l    = threadIdx.x & 15;
    const int node = blockIdx.x * 16 + sub;
    const bool valid = node < n;
    const int j = l * 8;

    float acc[8];
    #pragma unroll
    for (int k = 0; k < 8; ++k) acc[k] = 0.f;

    if (valid) {
        const int2 rp = rp2[node];            // one 8B load: {start, end}
        {   // self-loop term: hw[i] * dis_i^2
            const float d = dis[node];
            uint4 u = *(const uint4*)(hw + (size_t)node * DIM + j);
            acc8(acc, u, d * d);
        }

        const int pe = rp.y;
        for (int p = rp.x; p < pe; p += 8) {
            const int pm = pe - 1;
            int2 e[8];
            #pragma unroll
            for (int k = 0; k < 8; ++k) {
                int pk = p + k;
                e[k] = epack[pk < pm ? pk : pm];
            }
            uint4 u[8];
            #pragma unroll
            for (int k = 0; k < 8; ++k)
                u[k] = *(const uint4*)(hw + (size_t)e[k].x * DIM + j);
            #pragma unroll
            for (int k = 0; k < 8; ++k) {
                float w = (p + k < pe) ? __builtin_bit_cast(float, e[k].y) : 0.f;
                acc8(acc, u[k], w);
            }
        }

        float4 b0 = *(const float4*)(bias + j);
        float4 b1 = *(const float4*)(bias + j + 4);
        acc[0] += b0.x; acc[1] += b0.y; acc[2] += b0.z; acc[3] += b0.w;
        acc[4] += b1.x; acc[5] += b1.y; acc[6] += b1.z; acc[7] += b1.w;

        uint4 o;
        o.x = (unsigned int)f2bf(acc[0]) | ((unsigned int)f2bf(acc[1]) << 16);
        o.y = (unsigned int)f2bf(acc[2]) | ((unsigned int)f2bf(acc[3]) << 16);
        o.z = (unsigned int)f2bf(acc[4]) | ((unsigned int)f2bf(acc[5]) << 16);
        o.w = (unsigned int)f2bf(acc[6]) | ((unsigned int)f2bf(acc[7]) << 16);
        *(uint4*)(out + (size_t)node * DIM + j) = o;
    }

    // BN stats: row padded to 257 floats (4-way write conflicts max).
    __shared__ float red[16][257];
    #pragma unroll
    for (int k = 0; k < 8; ++k) {
        float a = valid ? acc[k] : 0.f;
        red[sub][j + k]       = a;
        red[sub][128 + j + k] = a * a;
    }
    __syncthreads();
    float t = 0.f;
    #pragma unroll
    for (int r = 0; r < 16; ++r) t += red[r][threadIdx.x];
    atomicAdd(&stat[(blockIdx.x & (STAT_COPIES - 1)) * 256 + threadIdx.x], t);
}

// ---------------- BN finalize: fold stats into scale/shift ----------------

__global__ void bn_finalize_kernel(const float* __restrict__ stat,
                                   const float* __restrict__ gamma,
                                   const float* __restrict__ beta,
                                   float* __restrict__ mi, int n) {
    int c = threadIdx.x;
    if (c < DIM) {
        float s = 0.f, q = 0.f;
        #pragma unroll 4
        for (int cp = 0; cp < STAT_COPIES; ++cp) {
            s += stat[cp * 256 + c];
            q += stat[cp * 256 + 128 + c];
        }
        float mean  = s / (float)n;
        float var   = q / (float)n - mean * mean;
        float istd  = rsqrtf(var + BN_EPS);
        float scale = gamma[c] * istd;
        mi[c]       = scale;
        mi[DIM + c] = fmaf(-mean, scale, beta[c]);   // shift
    }
}

// ---------------- K7: fused agg2 + GEMM2 (fp32, register-blocked phase 2) -------
// out = (A_hat·Z)·W2 + b2, Z = relu(BN(h1)) computed in-register during gather.
// Phase 2 round-9 lesson: unblocked fp32 GEMM re-streamed 256KB of W2 per block
// through L2 (~180us). Register blocking: thread (kq,subg,l), tid=kq*64+subg*16+l,
// owns 4 nodes x 8 cols over k in [kq*32,kq*32+32). Per k one wave (=kq) loads
// W2 row k coalesced (4-way same-addr lanes merged); W2 read ONCE per block
// (64KB). 4 kq-partials per output reduced through LDS.

__global__ __launch_bounds__(256) void agg2_gemm_kernel(
    const unsigned short* __restrict__ h1, const float* __restrict__ dis,
    const int2* __restrict__ rp2, const int2* __restrict__ epack,
    const float* __restrict__ W2,               // fp32, row-major [128][128]
    const float* __restrict__ mi,               // [0..127]=scale, [128..255]=shift
    const float* __restrict__ b2,
    float* __restrict__ out, int n)
{
    __shared__ float sSf[16][132];
    __shared__ float sP[4][16][132];
    const int tid  = threadIdx.x;
    const int sub  = tid >> 4;
    const int l    = tid & 15;
    const int node0 = blockIdx.x * 16;
    const int node = node0 + sub;
    const bool valid = node < n;
    const int j = l * 8;

    float sc[8], sh[8];
    #pragma unroll
    for (int k = 0; k < 8; ++k) { sc[k] = mi[j + k]; sh[k] = mi[128 + j + k]; }

    float acc[8];
    #pragma unroll
    for (int k = 0; k < 8; ++k) acc[k] = 0.f;

    if (valid) {
        const int2 rp = rp2[node];
        {   // self-loop: Z[node] * dis^2
            const float d = dis[node];
            const float dd = d * d;
            uint4 u = *(const uint4*)(h1 + (size_t)node * DIM + j);
            unsigned int a[4] = {u.x, u.y, u.z, u.w};
            #pragma unroll
            for (int k = 0; k < 4; ++k) {
                float z0 = fmaxf(fmaf(bf2f((unsigned short)(a[k] & 0xffff)), sc[2*k],   sh[2*k]),   0.f);
                float z1 = fmaxf(fmaf(bf2f((unsigned short)(a[k] >> 16)),    sc[2*k+1], sh[2*k+1]), 0.f);
                acc[2*k]   = fmaf(z0, dd, acc[2*k]);
                acc[2*k+1] = fmaf(z1, dd, acc[2*k+1]);
            }
        }

        const int pe = rp.y;
        for (int p = rp.x; p < pe; p += 8) {
            const int pm = pe - 1;
            int2 e[8];
            #pragma unroll
            for (int k = 0; k < 8; ++k) {
                int pk = p + k;
                e[k] = epack[pk < pm ? pk : pm];
            }
            uint4 u[8];
            #pragma unroll
            for (int k = 0; k < 8; ++k)
                u[k] = *(const uint4*)(h1 + (size_t)e[k].x * DIM + j);
            #pragma unroll
            for (int k = 0; k < 8; ++k) {
                float w = (p + k < pe) ? __builtin_bit_cast(float, e[k].y) : 0.f;
                unsigned int a[4] = {u[k].x, u[k].y, u[k].z, u[k].w};
                #pragma unroll
                for (int q = 0; q < 4; ++q) {
                    float z0 = fmaxf(fmaf(bf2f((unsigned short)(a[q] & 0xffff)), sc[2*q],   sh[2*q]),   0.f);
                    float z1 = fmaxf(fmaf(bf2f((unsigned short)(a[q] >> 16)),    sc[2*q+1], sh[2*q+1]), 0.f);
                    acc[2*q]   = fmaf(z0, w, acc[2*q]);
                    acc[2*q+1] = fmaf(z1, w, acc[2*q+1]);
                }
            }
        }
    }

    // stage fp32 S tile (invalid rows = 0)
    *(float4*)(&sSf[sub][j])     = make_float4(acc[0], acc[1], acc[2], acc[3]);
    *(float4*)(&sSf[sub][j + 4]) = make_float4(acc[4], acc[5], acc[6], acc[7]);
    __syncthreads();

    // ---- Phase 2: register-blocked fp32 GEMM ----
    {
        const int kq   = tid >> 6;          // wave id = k-quadrant
        const int subg = (tid >> 4) & 3;    // node group (4 nodes)
        const int l2   = tid & 15;
        const int jj   = l2 * 8;
        const int kb   = kq * 32;

        float pa[4][8];
        #pragma unroll
        for (int i = 0; i < 4; ++i)
            #pragma unroll
            for (int c = 0; c < 8; ++c) pa[i][c] = 0.f;

        for (int kk = 0; kk < 32; kk += 4) {
            floatx4 sv[4];
            #pragma unroll
            for (int i = 0; i < 4; ++i)
                sv[i] = *(const floatx4*)(&sSf[subg * 4 + i][kb + kk]);
            #pragma unroll
            for (int d = 0; d < 4; ++d) {
                const int k = kb + kk + d;
                float4 w0 = *(const float4*)(W2 + (size_t)k * DIM + jj);
                float4 w1 = *(const float4*)(W2 + (size_t)k * DIM + jj + 4);
                #pragma unroll
                for (int i = 0; i < 4; ++i) {
                    const float s = sv[i][d];
                    pa[i][0] = fmaf(s, w0.x, pa[i][0]);
                    pa[i][1] = fmaf(s, w0.y, pa[i][1]);
                    pa[i][2] = fmaf(s, w0.z, pa[i][2]);
                    pa[i][3] = fmaf(s, w0.w, pa[i][3]);
                    pa[i][4] = fmaf(s, w1.x, pa[i][4]);
                    pa[i][5] = fmaf(s, w1.y, pa[i][5]);
                    pa[i][6] = fmaf(s, w1.z, pa[i][6]);
                    pa[i][7] = fmaf(s, w1.w, pa[i][7]);
                }
            }
        }

        #pragma unroll
        for (int i = 0; i < 4; ++i) {
            *(float4*)(&sP[kq][subg * 4 + i][jj])     = make_float4(pa[i][0], pa[i][1], pa[i][2], pa[i][3]);
            *(float4*)(&sP[kq][subg * 4 + i][jj + 4]) = make_float4(pa[i][4], pa[i][5], pa[i][6], pa[i][7]);
        }
    }
    __syncthreads();

    // reduce 4 kq-partials, add b2, store
    if (valid) {
        float4 bb0 = *(const float4*)(b2 + j);
        float4 bb1 = *(const float4*)(b2 + j + 4);
        float o[8] = { bb0.x, bb0.y, bb0.z, bb0.w, bb1.x, bb1.y, bb1.z, bb1.w };
        #pragma unroll
        for (int kq = 0; kq < 4; ++kq) {
            floatx4 p0 = *(const floatx4*)(&sP[kq][sub][j]);
            floatx4 p1 = *(const floatx4*)(&sP[kq][sub][j + 4]);
            o[0] += p0[0]; o[1] += p0[1]; o[2] += p0[2]; o[3] += p0[3];
            o[4] += p1[0]; o[5] += p1[1]; o[6] += p1[2]; o[7] += p1[3];
        }
        *(float4*)(out + (size_t)node * DIM + j)     = make_float4(o[0], o[1], o[2], o[3]);
        *(float4*)(out + (size_t)node * DIM + j + 4) = make_float4(o[4], o[5], o[6], o[7]);
    }
}

// ---------------- launch ----------------

extern "C" void kernel_launch(void* const* d_in, const int* in_sizes, int n_in,
                              void* d_out, int out_size, void* d_ws, size_t ws_size,
                              hipStream_t stream)
{
    const float* x      = (const float*)d_in[0];
    const int*   ei     = (const int*)  d_in[1];
    const float* W1     = (const float*)d_in[2];
    const float* b1     = (const float*)d_in[3];
    const float* gamma1 = (const float*)d_in[4];
    const float* beta1  = (const float*)d_in[5];
    const float* W2     = (const float*)d_in[6];
    const float* b2     = (const float*)d_in[7];
    float* out = (float*)d_out;

    const int N = in_sizes[0] / DIM;   // 100000
    const int E = in_sizes[1] / 2;     // 600000
    const int* row = ei;
    const int* col = ei + E;

    const int NB    = (N + 1023) / 1024;   // <= 256 (N <= 262144)
    const int degB  = (E + 255) / 256;
    const int gemmB = (N + 63) / 64;
    const int aggB  = (N + 15) / 16;
    // interleaved K4 grid: groups of 5 = 3 scatter + 2 gemm
    const int k4B   = 5 * max((degB + 2) / 3, (gemmB + 1) / 2);

    // Workspace layout (8B-alignment-safe ordering). Zeroed region is contiguous:
    unsigned short* hw    = (unsigned short*)d_ws;         // N*128 bf16
    unsigned short* h1    = hw + (size_t)N * DIM;          // N*128 bf16
    int2*  epack  = (int2*)(h1 + (size_t)N * DIM);         // E (8B each)
    int2*  rp2    = epack + E;                             // N {start,end}
    unsigned short* wfrag = (unsigned short*)(rp2 + N);    // 16384 bf16 (W1 frags)
    float* dis    = (float*)(wfrag + 2 * 16384);           // N
    int*   rank   = (int*)(dis + N);                       // E (edge rank in bucket)
    int*   rowptr = rank + E;                              // N (scratch, per-block scan)
    int*   aux    = rowptr + N;                            // 256
    float* mi     = (float*)(aux + 256);                   // 256
    // ---- zeroed region start ----
    int*   deg    = (int*)(mi + 256);                      // N
    float* stat   = (float*)(deg + N);                     // 64*256
    const size_t zero_bytes = (size_t)N * 4 + (size_t)STAT_COPIES * 256 * 4;

    hipMemsetAsync(deg, 0, zero_bytes, stream);

    // K1: degree atomics (rank captured) + W1 fragment conversion
    deg_convw_kernel<<<degB + 8, 256, 0, stream>>>(row, deg, rank, E, degB, W1, wfrag);
    // K2: per-block exclusive scan (+ dis)
    scan_block_kernel<<<NB, 256, 0, stream>>>(deg, rowptr, aux, dis, N);
    // K3: cross-block offsets (self-computed aux prefix) -> rp2
    add_offsets_kernel<<<NB, 256, 0, stream>>>(rowptr, deg, aux, rp2, N);
    // K4: atomic-free scatter interleaved (mod-5) with LDS-free gemm1
    scatter_gemm1_kernel<<<k4B, 256, 0, stream>>>(row, col, rank, dis, rp2, epack, E, degB,
                                                  x, wfrag, hw, N, gemmB);
    // K5: agg layer 1 + fused BN stats (spread atomics, no fence)
    agg1_kernel<<<aggB, 256, 0, stream>>>(hw, dis, rp2, epack, b1, h1, N, stat);
    // K5b: fold stats -> BN scale/shift (1 tiny block; kernel boundary = coherence)
    bn_finalize_kernel<<<1, DIM, 0, stream>>>(stat, gamma1, beta1, mi, N);
    // K7: fused agg2+gemm2 (fp32 reg-blocked phase 2): out = (A_hat·Z)@W2 + b2
    agg2_gemm_kernel<<<aggB, 256, 0, stream>>>(h1, dis, rp2, epack, W2, mi, b2, out, N);
}

// Round 11
// 259.418 us; speedup vs baseline: 1.5903x; 1.1065x over previous
//
#include <hip/hip_runtime.h>

#define DIM 128
#define BN_EPS 1e-5f
#define STAT_COPIES 64

typedef short short8 __attribute__((ext_vector_type(8)));   // 8 bf16 bit patterns
typedef float floatx4 __attribute__((ext_vector_type(4)));

__device__ __forceinline__ unsigned short f2bf(float f) {
    unsigned int u = __builtin_bit_cast(unsigned int, f);
    u += 0x7FFFu + ((u >> 16) & 1u);          // RNE (inputs are finite)
    return (unsigned short)(u >> 16);
}
__device__ __forceinline__ float bf2f(unsigned short h) {
    return __builtin_bit_cast(float, (unsigned int)h << 16);
}

// ---------------- K1: degree (atomic, rank captured) + W->bf16 conversion ------
// rank[e] = edge's arrival index within its row bucket (free from atomicAdd
// return) -> scatter needs no second atomic pass.
// wfrag[((kt*8+nt)*64 + lane)*8 + j] = W[kt*32 + (lane>>4)*8 + j][nt*16 + (lane&15)]

__global__ __launch_bounds__(256) void deg_convw_kernel(
    const int* __restrict__ row, int* __restrict__ deg, int* __restrict__ rank,
    int E, int degB,
    const float* __restrict__ W1, const float* __restrict__ W2,
    unsigned short* __restrict__ wfrag)
{
    if ((int)blockIdx.x < degB) {
        int e = blockIdx.x * 256 + threadIdx.x;
        if (e < E) rank[e] = atomicAdd(&deg[row[e]], 1);
    } else {
        int s = (blockIdx.x - degB) * 256 + threadIdx.x;   // 0..4095
        if (s >= 4096) return;
        int m  = s >> 11;
        int s2 = s & 2047;
        int kt = s2 >> 9;
        int nt = (s2 >> 6) & 7;
        int l  = s2 & 63;
        const float* W = m ? W2 : W1;
        unsigned short* o = wfrag + (size_t)m * 16384 + (size_t)s2 * 8;
        int k0 = kt * 32 + (l >> 4) * 8;
        int n0 = nt * 16 + (l & 15);
        #pragma unroll
        for (int j = 0; j < 8; ++j) o[j] = f2bf(W[(k0 + j) * DIM + n0]);
    }
}

// ---------------- K2: per-block exclusive scan over deg (+ fused dis) ----------

__global__ __launch_bounds__(256) void scan_block_kernel(const int* __restrict__ deg,
                                                         int* __restrict__ rowptr,
                                                         int* __restrict__ aux,
                                                         float* __restrict__ dis, int n) {
    __shared__ int ls[256];
    const int base = blockIdx.x * 1024;
    const int t = threadIdx.x;
    int v[4]; int s = 0;
    #pragma unroll
    for (int k = 0; k < 4; ++k) {
        int i = base + t * 4 + k;
        v[k] = (i < n) ? deg[i] : 0;
        s += v[k];
    }
    ls[t] = s;
    __syncthreads();
    for (int off = 1; off < 256; off <<= 1) {
        int x = (t >= off) ? ls[t - off] : 0;
        __syncthreads();
        ls[t] += x;
        __syncthreads();
    }
    int excl = ls[t] - s;
    if (t == 255) aux[blockIdx.x] = ls[255];
    #pragma unroll
    for (int k = 0; k < 4; ++k) {
        int i = base + t * 4 + k;
        if (i < n) {
            rowptr[i] = excl;
            dis[i] = rsqrtf((float)(v[k] + 1));   // +1 self-loop; always > 0
        }
        excl += v[k];
    }
}

// ---------------- K3: add aux prefix (computed per-block), build rp2 ----------

__global__ __launch_bounds__(256) void add_offsets_kernel(
    const int* __restrict__ rowptr, const int* __restrict__ deg,
    const int* __restrict__ aux, int2* __restrict__ rp2, int n)
{
    __shared__ int red[256];
    const int t = threadIdx.x;
    red[t] = (t < (int)blockIdx.x) ? aux[t] : 0;   // blockIdx <= 255 by construction
    __syncthreads();
    for (int off = 128; off > 0; off >>= 1) {
        if (t < off) red[t] += red[t + off];
        __syncthreads();
    }
    const int base = red[0];
    #pragma unroll
    for (int k = 0; k < 4; ++k) {
        int i = blockIdx.x * 1024 + t * 4 + k;
        if (i < n) {
            int st = rowptr[i] + base;
            rp2[i] = make_int2(st, st + deg[i]);
        }
    }
}

// ---------------- K4: scatter (atomic-free, 2 edges/thread) + gemm1, interleaved
// mod-5 block mapping: 3 scatter : 2 gemm so every CU holds a mix from t=0.
// Scatter: 2 independent edge chains per thread (round-11: doubles MLP in the
// dependent random-load chain). GEMM: direct fragment loads, no LDS, no barrier.

__global__ __launch_bounds__(256) void scatter_gemm1_kernel(
    const int* __restrict__ row, const int* __restrict__ col,
    const int* __restrict__ rank, const float* __restrict__ dis,
    const int2* __restrict__ rp2, int2* __restrict__ epack, int E, int scatS,
    const float* __restrict__ A, const unsigned short* __restrict__ wfrag,
    unsigned short* __restrict__ C, int n, int gemmG)
{
    const int grp = blockIdx.x / 5;
    const int off = blockIdx.x % 5;
    if (off < 3) {
        const int sId = grp * 3 + off;
        if (sId >= scatS) return;
        const int e0 = sId * 512 + threadIdx.x;
        const int e1 = e0 + 256;
        const bool v0 = e0 < E, v1 = e1 < E;
        int r0 = 0, c0 = 0, k0 = 0, r1 = 0, c1 = 0, k1 = 0;
        if (v0) { r0 = row[e0]; c0 = col[e0]; k0 = rank[e0]; }
        if (v1) { r1 = row[e1]; c1 = col[e1]; k1 = rank[e1]; }
        int p0 = 0, p1 = 0;
        float d0r = 0.f, d0c = 0.f, d1r = 0.f, d1c = 0.f;
        if (v0) { p0 = rp2[r0].x + k0; d0r = dis[r0]; d0c = dis[c0]; }
        if (v1) { p1 = rp2[r1].x + k1; d1r = dis[r1]; d1c = dis[c1]; }
        if (v0) epack[p0] = make_int2(c0, __builtin_bit_cast(int, d0r * d0c));
        if (v1) epack[p1] = make_int2(c1, __builtin_bit_cast(int, d1r * d1c));
    } else {
        const int gId = grp * 2 + (off - 3);
        if (gId >= gemmG) return;
        const int tid  = threadIdx.x;
        const int row0 = gId * 64;
        const int wave = tid >> 6;
        const int lane = tid & 63;
        const int m    = lane & 15;
        const int quad = lane >> 4;
        const int rowA = row0 + wave * 16 + m;

        short8 af[4];
        if (rowA < n) {
            #pragma unroll
            for (int kt = 0; kt < 4; ++kt) {
                const float* src = A + (size_t)rowA * DIM + kt * 32 + quad * 8;
                float4 v0 = *(const float4*)(src);
                float4 v1 = *(const float4*)(src + 4);
                af[kt] = (short8){ (short)f2bf(v0.x), (short)f2bf(v0.y),
                                   (short)f2bf(v0.z), (short)f2bf(v0.w),
                                   (short)f2bf(v1.x), (short)f2bf(v1.y),
                                   (short)f2bf(v1.z), (short)f2bf(v1.w) };
            }
        } else {
            #pragma unroll
            for (int kt = 0; kt < 4; ++kt) af[kt] = (short8){0,0,0,0,0,0,0,0};
        }

        floatx4 acc[8];
        #pragma unroll
        for (int nt = 0; nt < 8; ++nt) acc[nt] = (floatx4){0.f, 0.f, 0.f, 0.f};

        #pragma unroll
        for (int nt = 0; nt < 8; ++nt)
            #pragma unroll
            for (int kt = 0; kt < 4; ++kt) {
                short8 bfr = *(const short8*)(wfrag + ((size_t)(kt * 8 + nt) * 64 + lane) * 8);
                acc[nt] = __builtin_amdgcn_mfma_f32_16x16x32_bf16(af[kt], bfr, acc[nt], 0, 0, 0);
            }

        #pragma unroll
        for (int nt = 0; nt < 8; ++nt)
            #pragma unroll
            for (int r = 0; r < 4; ++r) {
                int rr = row0 + wave * 16 + quad * 4 + r;
                if (rr < n) C[(size_t)rr * DIM + nt * 16 + m] = f2bf(acc[nt][r]);
            }
    }
}

// ---------------- K6: MFMA GEMM layer 2, direct bf16 fragment loads ------------
// BN scale/shift + ReLU applied in-register on the A fragment (verified path,
// round 6: absmax 0.03125). No LDS, no barrier.

__global__ __launch_bounds__(256) void gemm_mfma_bn_kernel(
    const unsigned short* __restrict__ Abf, const unsigned short* __restrict__ wfrag,
    unsigned short* __restrict__ C, int n,
    const float* __restrict__ mi)   // mi[0..127]=scale, mi[128..255]=shift
{
    const int tid  = threadIdx.x;
    const int row0 = blockIdx.x * 64;
    const int wave = tid >> 6;
    const int lane = tid & 63;
    const int m    = lane & 15;
    const int quad = lane >> 4;
    const int rowA = row0 + wave * 16 + m;

    short8 af[4];
    if (rowA < n) {
        #pragma unroll
        for (int kt = 0; kt < 4; ++kt) {
            const int c0 = kt * 32 + quad * 8;
            short8 v = *(const short8*)(Abf + (size_t)rowA * DIM + c0);
            float4 s0 = *(const float4*)(mi + c0);
            float4 s1 = *(const float4*)(mi + c0 + 4);
            float4 h0 = *(const float4*)(mi + 128 + c0);
            float4 h1 = *(const float4*)(mi + 128 + c0 + 4);
            float f[8];
            #pragma unroll
            for (int j = 0; j < 8; ++j) f[j] = bf2f((unsigned short)v[j]);
            f[0] = fmaxf(fmaf(f[0], s0.x, h0.x), 0.f);
            f[1] = fmaxf(fmaf(f[1], s0.y, h0.y), 0.f);
            f[2] = fmaxf(fmaf(f[2], s0.z, h0.z), 0.f);
            f[3] = fmaxf(fmaf(f[3], s0.w, h0.w), 0.f);
            f[4] = fmaxf(fmaf(f[4], s1.x, h1.x), 0.f);
            f[5] = fmaxf(fmaf(f[5], s1.y, h1.y), 0.f);
            f[6] = fmaxf(fmaf(f[6], s1.z, h1.z), 0.f);
            f[7] = fmaxf(fmaf(f[7], s1.w, h1.w), 0.f);
            af[kt] = (short8){ (short)f2bf(f[0]), (short)f2bf(f[1]),
                               (short)f2bf(f[2]), (short)f2bf(f[3]),
                               (short)f2bf(f[4]), (short)f2bf(f[5]),
                               (short)f2bf(f[6]), (short)f2bf(f[7]) };
        }
    } else {
        #pragma unroll
        for (int kt = 0; kt < 4; ++kt) af[kt] = (short8){0,0,0,0,0,0,0,0};
    }

    floatx4 acc[8];
    #pragma unroll
    for (int nt = 0; nt < 8; ++nt) acc[nt] = (floatx4){0.f, 0.f, 0.f, 0.f};

    #pragma unroll
    for (int nt = 0; nt < 8; ++nt)
        #pragma unroll
        for (int kt = 0; kt < 4; ++kt) {
            short8 bfr = *(const short8*)(wfrag + ((size_t)(kt * 8 + nt) * 64 + lane) * 8);
            acc[nt] = __builtin_amdgcn_mfma_f32_16x16x32_bf16(af[kt], bfr, acc[nt], 0, 0, 0);
        }

    #pragma unroll
    for (int nt = 0; nt < 8; ++nt)
        #pragma unroll
        for (int r = 0; r < 4; ++r) {
            int rr = row0 + wave * 16 + quad * 4 + r;
            if (rr < n) C[(size_t)rr * DIM + nt * 16 + m] = f2bf(acc[nt][r]);
        }
}

// ---------------- K5/K7: CSR aggregation ----------------
// 16 lanes/node, 8 ch/lane. out[i] = sum_e hw[col_e]*norm_e + hw[i]*dis_i^2 + bias.
// Uniform predicated unroll-8 loop: index clamped to pe-1, weight 0 for pad slots.
// STATS: LDS reduce + atomics over 64 spread copies. NO per-block threadfence
// (round-3 lesson: 6250x buffer_wbl2 serialized at the TCC = +620us).

__device__ __forceinline__ void acc8(float* acc, uint4 u, float w) {
    unsigned int a[4] = {u.x, u.y, u.z, u.w};
    #pragma unroll
    for (int k = 0; k < 4; ++k) {
        acc[2*k]   = fmaf(bf2f((unsigned short)(a[k] & 0xffff)), w, acc[2*k]);
        acc[2*k+1] = fmaf(bf2f((unsigned short)(a[k] >> 16)),    w, acc[2*k+1]);
    }
}

template <bool OUT_BF16, bool STATS>
__global__ __launch_bounds__(256) void agg_csr_kernel(
    const unsigned short* __restrict__ hw, const float* __restrict__ dis,
    const int2* __restrict__ rp2, const int2* __restrict__ epack,
    const float* __restrict__ bias, void* __restrict__ out_, int n,
    float* __restrict__ stat)
{
    const int sub  = threadIdx.x >> 4;        // 0..15 node slot in block
    const int l    = threadIdx.x & 15;
    const int node = blockIdx.x * 16 + sub;
    const bool valid = node < n;
    const int j = l * 8;

    float acc[8];
    #pragma unroll
    for (int k = 0; k < 8; ++k) acc[k] = 0.f;

    if (valid) {
        const int2 rp = rp2[node];            // one 8B load: {start, end}
        {   // self-loop term: hw[i] * dis_i^2
            const float d = dis[node];
            uint4 u = *(const uint4*)(hw + (size_t)node * DIM + j);
            acc8(acc, u, d * d);
        }

        const int pe = rp.y;
        for (int p = rp.x; p < pe; p += 8) {
            const int pm = pe - 1;
            int2 e[8];
            #pragma unroll
            for (int k = 0; k < 8; ++k) {
                int pk = p + k;
                e[k] = epack[pk < pm ? pk : pm];
            }
            uint4 u[8];
            #pragma unroll
            for (int k = 0; k < 8; ++k)
                u[k] = *(const uint4*)(hw + (size_t)e[k].x * DIM + j);
            #pragma unroll
            for (int k = 0; k < 8; ++k) {
                float w = (p + k < pe) ? __builtin_bit_cast(float, e[k].y) : 0.f;
                acc8(acc, u[k], w);
            }
        }

        float4 b0 = *(const float4*)(bias + j);
        float4 b1 = *(const float4*)(bias + j + 4);
        acc[0] += b0.x; acc[1] += b0.y; acc[2] += b0.z; acc[3] += b0.w;
        acc[4] += b1.x; acc[5] += b1.y; acc[6] += b1.z; acc[7] += b1.w;

        if (OUT_BF16) {
            unsigned short* out = (unsigned short*)out_;
            uint4 o;
            o.x = (unsigned int)f2bf(acc[0]) | ((unsigned int)f2bf(acc[1]) << 16);
            o.y = (unsigned int)f2bf(acc[2]) | ((unsigned int)f2bf(acc[3]) << 16);
            o.z = (unsigned int)f2bf(acc[4]) | ((unsigned int)f2bf(acc[5]) << 16);
            o.w = (unsigned int)f2bf(acc[6]) | ((unsigned int)f2bf(acc[7]) << 16);
            *(uint4*)(out + (size_t)node * DIM + j) = o;
        } else {
            float* out = (float*)out_;
            *(float4*)(out + (size_t)node * DIM + j)     = make_float4(acc[0], acc[1], acc[2], acc[3]);
            *(float4*)(out + (size_t)node * DIM + j + 4) = make_float4(acc[4], acc[5], acc[6], acc[7]);
        }
    }

    if constexpr (STATS) {
        // row padded to 257 floats: 4-way write conflicts max, reads ~free.
        __shared__ float red[16][257];
        #pragma unroll
        for (int k = 0; k < 8; ++k) {
            float a = valid ? acc[k] : 0.f;
            red[sub][j + k]       = a;
            red[sub][128 + j + k] = a * a;
        }
        __syncthreads();
        float t = 0.f;
        #pragma unroll
        for (int r = 0; r < 16; ++r) t += red[r][threadIdx.x];
        atomicAdd(&stat[(blockIdx.x & (STAT_COPIES - 1)) * 256 + threadIdx.x], t);
    }
}

// ---------------- BN finalize: fold stats into scale/shift ----------------

__global__ void bn_finalize_kernel(const float* __restrict__ stat,
                                   const float* __restrict__ gamma,
                                   const float* __restrict__ beta,
                                   float* __restrict__ mi, int n) {
    int c = threadIdx.x;
    if (c < DIM) {
        float s = 0.f, q = 0.f;
        #pragma unroll 4
        for (int cp = 0; cp < STAT_COPIES; ++cp) {
            s += stat[cp * 256 + c];
            q += stat[cp * 256 + 128 + c];
        }
        float mean  = s / (float)n;
        float var   = q / (float)n - mean * mean;
        float istd  = rsqrtf(var + BN_EPS);
        float scale = gamma[c] * istd;
        mi[c]       = scale;
        mi[DIM + c] = fmaf(-mean, scale, beta[c]);   // shift
    }
}

// ---------------- launch ----------------

extern "C" void kernel_launch(void* const* d_in, const int* in_sizes, int n_in,
                              void* d_out, int out_size, void* d_ws, size_t ws_size,
                              hipStream_t stream)
{
    const float* x      = (const float*)d_in[0];
    const int*   ei     = (const int*)  d_in[1];
    const float* W1     = (const float*)d_in[2];
    const float* b1     = (const float*)d_in[3];
    const float* gamma1 = (const float*)d_in[4];
    const float* beta1  = (const float*)d_in[5];
    const float* W2     = (const float*)d_in[6];
    const float* b2     = (const float*)d_in[7];
    float* out = (float*)d_out;

    const int N = in_sizes[0] / DIM;   // 100000
    const int E = in_sizes[1] / 2;     // 600000
    const int* row = ei;
    const int* col = ei + E;

    const int NB    = (N + 1023) / 1024;   // <= 256 (N <= 262144)
    const int degB  = (E + 255) / 256;
    const int scatB = (E + 511) / 512;     // 2 edges/thread
    const int gemmB = (N + 63) / 64;
    const int aggB  = (N + 15) / 16;
    // interleaved K4 grid: groups of 5 = 3 scatter + 2 gemm
    const int k4B   = 5 * max((scatB + 2) / 3, (gemmB + 1) / 2);

    // Workspace layout (8B-alignment-safe ordering). Zeroed region is contiguous:
    unsigned short* hw    = (unsigned short*)d_ws;         // N*128 bf16
    unsigned short* h1    = hw + (size_t)N * DIM;          // N*128 bf16
    int2*  epack  = (int2*)(h1 + (size_t)N * DIM);         // E (8B each)
    int2*  rp2    = epack + E;                             // N {start,end}
    unsigned short* wfrag = (unsigned short*)(rp2 + N);    // 2*16384 bf16
    float* dis    = (float*)(wfrag + 2 * 16384);           // N
    int*   rank   = (int*)(dis + N);                       // E (edge rank in bucket)
    int*   rowptr = rank + E;                              // N (scratch, per-block scan)
    int*   aux    = rowptr + N;                            // 256
    float* mi     = (float*)(aux + 256);                   // 256
    // ---- zeroed region start ----
    int*   deg    = (int*)(mi + 256);                      // N
    float* stat   = (float*)(deg + N);                     // 64*256
    const size_t zero_bytes = (size_t)N * 4 + (size_t)STAT_COPIES * 256 * 4;

    hipMemsetAsync(deg, 0, zero_bytes, stream);

    // K1: degree atomics (rank captured) + W conversion
    deg_convw_kernel<<<degB + 16, 256, 0, stream>>>(row, deg, rank, E, degB, W1, W2, wfrag);
    // K2: per-block exclusive scan (+ dis)
    scan_block_kernel<<<NB, 256, 0, stream>>>(deg, rowptr, aux, dis, N);
    // K3: cross-block offsets (self-computed aux prefix) -> rp2
    add_offsets_kernel<<<NB, 256, 0, stream>>>(rowptr, deg, aux, rp2, N);
    // K4: atomic-free scatter (2 edges/thread) interleaved (mod-5) with gemm1
    scatter_gemm1_kernel<<<k4B, 256, 0, stream>>>(row, col, rank, dis, rp2, epack, E, scatB,
                                                  x, wfrag, hw, N, gemmB);
    // K5: agg layer 1 + fused BN stats (spread atomics, no fence)
    agg_csr_kernel<true, true><<<aggB, 256, 0, stream>>>(hw, dis, rp2, epack, b1, h1, N,
                                                         stat);
    // K5b: fold stats -> BN scale/shift (1 tiny block; kernel boundary = coherence)
    bn_finalize_kernel<<<1, DIM, 0, stream>>>(stat, gamma1, beta1, mi, N);
    // K6: gemm2 with in-register BN(scale,shift)+ReLU, LDS-free
    gemm_mfma_bn_kernel<<<gemmB, 256, 0, stream>>>(h1, wfrag + 16384, hw, N, mi);
    // K7: agg layer 2 -> fp32 output
    agg_csr_kernel<false, false><<<aggB, 256, 0, stream>>>(hw, dis, rp2, epack, b2, out, N,
                                                           nullptr);
}

// Round 12
// 259.067 us; speedup vs baseline: 1.5925x; 1.0014x over previous
//
#include <hip/hip_runtime.h>

#define DIM 128
#define BN_EPS 1e-5f
#define STAT_COPIES 64

typedef short short8 __attribute__((ext_vector_type(8)));   // 8 bf16 bit patterns
typedef float floatx4 __attribute__((ext_vector_type(4)));

__device__ __forceinline__ unsigned short f2bf(float f) {
    unsigned int u = __builtin_bit_cast(unsigned int, f);
    u += 0x7FFFu + ((u >> 16) & 1u);          // RNE (inputs are finite)
    return (unsigned short)(u >> 16);
}
__device__ __forceinline__ float bf2f(unsigned short h) {
    return __builtin_bit_cast(float, (unsigned int)h << 16);
}

// ---------------- K1: degree (atomic, rank captured) + W->bf16 conversion ------
// rank[e] = edge's arrival index within its row bucket (free from atomicAdd
// return) -> scatter needs no second atomic pass.
// wfrag[((kt*8+nt)*64 + lane)*8 + j] = W[kt*32 + (lane>>4)*8 + j][nt*16 + (lane&15)]

__global__ __launch_bounds__(256) void deg_convw_kernel(
    const int* __restrict__ row, int* __restrict__ deg, int* __restrict__ rank,
    int E, int degB,
    const float* __restrict__ W1, const float* __restrict__ W2,
    unsigned short* __restrict__ wfrag)
{
    if ((int)blockIdx.x < degB) {
        int e = blockIdx.x * 256 + threadIdx.x;
        if (e < E) rank[e] = atomicAdd(&deg[row[e]], 1);
    } else {
        int s = (blockIdx.x - degB) * 256 + threadIdx.x;   // 0..4095
        if (s >= 4096) return;
        int m  = s >> 11;
        int s2 = s & 2047;
        int kt = s2 >> 9;
        int nt = (s2 >> 6) & 7;
        int l  = s2 & 63;
        const float* W = m ? W2 : W1;
        unsigned short* o = wfrag + (size_t)m * 16384 + (size_t)s2 * 8;
        int k0 = kt * 32 + (l >> 4) * 8;
        int n0 = nt * 16 + (l & 15);
        #pragma unroll
        for (int j = 0; j < 8; ++j) o[j] = f2bf(W[(k0 + j) * DIM + n0]);
    }
}

// ---------------- K2: per-block exclusive scan over deg (+ fused dis) ----------

__global__ __launch_bounds__(256) void scan_block_kernel(const int* __restrict__ deg,
                                                         int* __restrict__ rowptr,
                                                         int* __restrict__ aux,
                                                         float* __restrict__ dis, int n) {
    __shared__ int ls[256];
    const int base = blockIdx.x * 1024;
    const int t = threadIdx.x;
    int v[4]; int s = 0;
    #pragma unroll
    for (int k = 0; k < 4; ++k) {
        int i = base + t * 4 + k;
        v[k] = (i < n) ? deg[i] : 0;
        s += v[k];
    }
    ls[t] = s;
    __syncthreads();
    for (int off = 1; off < 256; off <<= 1) {
        int x = (t >= off) ? ls[t - off] : 0;
        __syncthreads();
        ls[t] += x;
        __syncthreads();
    }
    int excl = ls[t] - s;
    if (t == 255) aux[blockIdx.x] = ls[255];
    #pragma unroll
    for (int k = 0; k < 4; ++k) {
        int i = base + t * 4 + k;
        if (i < n) {
            rowptr[i] = excl;
            dis[i] = rsqrtf((float)(v[k] + 1));   // +1 self-loop; always > 0
        }
        excl += v[k];
    }
}

// ---------------- K3: add aux prefix (computed per-block), build rp2 ----------

__global__ __launch_bounds__(256) void add_offsets_kernel(
    const int* __restrict__ rowptr, const int* __restrict__ deg,
    const int* __restrict__ aux, int2* __restrict__ rp2, int n)
{
    __shared__ int red[256];
    const int t = threadIdx.x;
    red[t] = (t < (int)blockIdx.x) ? aux[t] : 0;   // blockIdx <= 255 by construction
    __syncthreads();
    for (int off = 128; off > 0; off >>= 1) {
        if (t < off) red[t] += red[t + off];
        __syncthreads();
    }
    const int base = red[0];
    #pragma unroll
    for (int k = 0; k < 4; ++k) {
        int i = blockIdx.x * 1024 + t * 4 + k;
        if (i < n) {
            int st = rowptr[i] + base;
            rp2[i] = make_int2(st, st + deg[i]);
        }
    }
}

// ---------------- K4: scatter (atomic-free, 2 edges/thread) + gemm1, interleaved
// mod-5 mapping 2 scatter : 3 gemm (matches 1172:1563 block ratio; round-12 fix:
// the old 3:2 split launched 1174 dead blocks). Scatter: 2 independent edge
// chains per thread. GEMM: direct fragment loads, no LDS, no barrier; epilogue
// stores iterate r-outer/nt-inner so the 8x32B stores covering one 256B row
// issue back-to-back (write-combining; round-11 WRITE_SIZE was +15MB amplified).

__global__ __launch_bounds__(256) void scatter_gemm1_kernel(
    const int* __restrict__ row, const int* __restrict__ col,
    const int* __restrict__ rank, const float* __restrict__ dis,
    const int2* __restrict__ rp2, int2* __restrict__ epack, int E, int scatS,
    const float* __restrict__ A, const unsigned short* __restrict__ wfrag,
    unsigned short* __restrict__ C, int n, int gemmG)
{
    const int grp = blockIdx.x / 5;
    const int off = blockIdx.x % 5;
    if (off < 2) {
        const int sId = grp * 2 + off;
        if (sId >= scatS) return;
        const int e0 = sId * 512 + threadIdx.x;
        const int e1 = e0 + 256;
        const bool v0 = e0 < E, v1 = e1 < E;
        int r0 = 0, c0 = 0, k0 = 0, r1 = 0, c1 = 0, k1 = 0;
        if (v0) { r0 = row[e0]; c0 = col[e0]; k0 = rank[e0]; }
        if (v1) { r1 = row[e1]; c1 = col[e1]; k1 = rank[e1]; }
        int p0 = 0, p1 = 0;
        float d0r = 0.f, d0c = 0.f, d1r = 0.f, d1c = 0.f;
        if (v0) { p0 = rp2[r0].x + k0; d0r = dis[r0]; d0c = dis[c0]; }
        if (v1) { p1 = rp2[r1].x + k1; d1r = dis[r1]; d1c = dis[c1]; }
        if (v0) epack[p0] = make_int2(c0, __builtin_bit_cast(int, d0r * d0c));
        if (v1) epack[p1] = make_int2(c1, __builtin_bit_cast(int, d1r * d1c));
    } else {
        const int gId = grp * 3 + (off - 2);
        if (gId >= gemmG) return;
        const int tid  = threadIdx.x;
        const int row0 = gId * 64;
        const int wave = tid >> 6;
        const int lane = tid & 63;
        const int m    = lane & 15;
        const int quad = lane >> 4;
        const int rowA = row0 + wave * 16 + m;

        short8 af[4];
        if (rowA < n) {
            #pragma unroll
            for (int kt = 0; kt < 4; ++kt) {
                const float* src = A + (size_t)rowA * DIM + kt * 32 + quad * 8;
                float4 v0 = *(const float4*)(src);
                float4 v1 = *(const float4*)(src + 4);
                af[kt] = (short8){ (short)f2bf(v0.x), (short)f2bf(v0.y),
                                   (short)f2bf(v0.z), (short)f2bf(v0.w),
                                   (short)f2bf(v1.x), (short)f2bf(v1.y),
                                   (short)f2bf(v1.z), (short)f2bf(v1.w) };
            }
        } else {
            #pragma unroll
            for (int kt = 0; kt < 4; ++kt) af[kt] = (short8){0,0,0,0,0,0,0,0};
        }

        floatx4 acc[8];
        #pragma unroll
        for (int nt = 0; nt < 8; ++nt) acc[nt] = (floatx4){0.f, 0.f, 0.f, 0.f};

        #pragma unroll
        for (int nt = 0; nt < 8; ++nt)
            #pragma unroll
            for (int kt = 0; kt < 4; ++kt) {
                short8 bfr = *(const short8*)(wfrag + ((size_t)(kt * 8 + nt) * 64 + lane) * 8);
                acc[nt] = __builtin_amdgcn_mfma_f32_16x16x32_bf16(af[kt], bfr, acc[nt], 0, 0, 0);
            }

        // r-outer / nt-inner: 8 stores covering one 256B row issue back-to-back
        #pragma unroll
        for (int r = 0; r < 4; ++r) {
            int rr = row0 + wave * 16 + quad * 4 + r;
            if (rr < n) {
                #pragma unroll
                for (int nt = 0; nt < 8; ++nt)
                    C[(size_t)rr * DIM + nt * 16 + m] = f2bf(acc[nt][r]);
            }
        }
    }
}

// ---------------- K6: MFMA GEMM layer 2, direct bf16 fragment loads ------------
// BN scale/shift + ReLU applied in-register on the A fragment (verified path,
// round 6: absmax 0.03125). No LDS, no barrier. r-outer store order (round 12).

__global__ __launch_bounds__(256) void gemm_mfma_bn_kernel(
    const unsigned short* __restrict__ Abf, const unsigned short* __restrict__ wfrag,
    unsigned short* __restrict__ C, int n,
    const float* __restrict__ mi)   // mi[0..127]=scale, mi[128..255]=shift
{
    const int tid  = threadIdx.x;
    const int row0 = blockIdx.x * 64;
    const int wave = tid >> 6;
    const int lane = tid & 63;
    const int m    = lane & 15;
    const int quad = lane >> 4;
    const int rowA = row0 + wave * 16 + m;

    short8 af[4];
    if (rowA < n) {
        #pragma unroll
        for (int kt = 0; kt < 4; ++kt) {
            const int c0 = kt * 32 + quad * 8;
            short8 v = *(const short8*)(Abf + (size_t)rowA * DIM + c0);
            float4 s0 = *(const float4*)(mi + c0);
            float4 s1 = *(const float4*)(mi + c0 + 4);
            float4 h0 = *(const float4*)(mi + 128 + c0);
            float4 h1 = *(const float4*)(mi + 128 + c0 + 4);
            float f[8];
            #pragma unroll
            for (int j = 0; j < 8; ++j) f[j] = bf2f((unsigned short)v[j]);
            f[0] = fmaxf(fmaf(f[0], s0.x, h0.x), 0.f);
            f[1] = fmaxf(fmaf(f[1], s0.y, h0.y), 0.f);
            f[2] = fmaxf(fmaf(f[2], s0.z, h0.z), 0.f);
            f[3] = fmaxf(fmaf(f[3], s0.w, h0.w), 0.f);
            f[4] = fmaxf(fmaf(f[4], s1.x, h1.x), 0.f);
            f[5] = fmaxf(fmaf(f[5], s1.y, h1.y), 0.f);
            f[6] = fmaxf(fmaf(f[6], s1.z, h1.z), 0.f);
            f[7] = fmaxf(fmaf(f[7], s1.w, h1.w), 0.f);
            af[kt] = (short8){ (short)f2bf(f[0]), (short)f2bf(f[1]),
                               (short)f2bf(f[2]), (short)f2bf(f[3]),
                               (short)f2bf(f[4]), (short)f2bf(f[5]),
                               (short)f2bf(f[6]), (short)f2bf(f[7]) };
        }
    } else {
        #pragma unroll
        for (int kt = 0; kt < 4; ++kt) af[kt] = (short8){0,0,0,0,0,0,0,0};
    }

    floatx4 acc[8];
    #pragma unroll
    for (int nt = 0; nt < 8; ++nt) acc[nt] = (floatx4){0.f, 0.f, 0.f, 0.f};

    #pragma unroll
    for (int nt = 0; nt < 8; ++nt)
        #pragma unroll
        for (int kt = 0; kt < 4; ++kt) {
            short8 bfr = *(const short8*)(wfrag + ((size_t)(kt * 8 + nt) * 64 + lane) * 8);
            acc[nt] = __builtin_amdgcn_mfma_f32_16x16x32_bf16(af[kt], bfr, acc[nt], 0, 0, 0);
        }

    #pragma unroll
    for (int r = 0; r < 4; ++r) {
        int rr = row0 + wave * 16 + quad * 4 + r;
        if (rr < n) {
            #pragma unroll
            for (int nt = 0; nt < 8; ++nt)
                C[(size_t)rr * DIM + nt * 16 + m] = f2bf(acc[nt][r]);
        }
    }
}

// ---------------- K5/K7: CSR aggregation ----------------
// 16 lanes/node, 8 ch/lane. out[i] = sum_e hw[col_e]*norm_e + hw[i]*dis_i^2 + bias.
// Uniform predicated unroll-8 loop: index clamped to pe-1, weight 0 for pad slots.
// STATS: LDS reduce + atomics over 64 spread copies. NO per-block threadfence
// (round-3 lesson: 6250x buffer_wbl2 serialized at the TCC = +620us).

__device__ __forceinline__ void acc8(float* acc, uint4 u, float w) {
    unsigned int a[4] = {u.x, u.y, u.z, u.w};
    #pragma unroll
    for (int k = 0; k < 4; ++k) {
        acc[2*k]   = fmaf(bf2f((unsigned short)(a[k] & 0xffff)), w, acc[2*k]);
        acc[2*k+1] = fmaf(bf2f((unsigned short)(a[k] >> 16)),    w, acc[2*k+1]);
    }
}

template <bool OUT_BF16, bool STATS>
__global__ __launch_bounds__(256) void agg_csr_kernel(
    const unsigned short* __restrict__ hw, const float* __restrict__ dis,
    const int2* __restrict__ rp2, const int2* __restrict__ epack,
    const float* __restrict__ bias, void* __restrict__ out_, int n,
    float* __restrict__ stat)
{
    const int sub  = threadIdx.x >> 4;        // 0..15 node slot in block
    const int l    = threadIdx.x & 15;
    const int node = blockIdx.x * 16 + sub;
    const bool valid = node < n;
    const int j = l * 8;

    float acc[8];
    #pragma unroll
    for (int k = 0; k < 8; ++k) acc[k] = 0.f;

    if (valid) {
        const int2 rp = rp2[node];            // one 8B load: {start, end}
        {   // self-loop term: hw[i] * dis_i^2
            const float d = dis[node];
            uint4 u = *(const uint4*)(hw + (size_t)node * DIM + j);
            acc8(acc, u, d * d);
        }

        const int pe = rp.y;
        for (int p = rp.x; p < pe; p += 8) {
            const int pm = pe - 1;
            int2 e[8];
            #pragma unroll
            for (int k = 0; k < 8; ++k) {
                int pk = p + k;
                e[k] = epack[pk < pm ? pk : pm];
            }
            uint4 u[8];
            #pragma unroll
            for (int k = 0; k < 8; ++k)
                u[k] = *(const uint4*)(hw + (size_t)e[k].x * DIM + j);
            #pragma unroll
            for (int k = 0; k < 8; ++k) {
                float w = (p + k < pe) ? __builtin_bit_cast(float, e[k].y) : 0.f;
                acc8(acc, u[k], w);
            }
        }

        float4 b0 = *(const float4*)(bias + j);
        float4 b1 = *(const float4*)(bias + j + 4);
        acc[0] += b0.x; acc[1] += b0.y; acc[2] += b0.z; acc[3] += b0.w;
        acc[4] += b1.x; acc[5] += b1.y; acc[6] += b1.z; acc[7] += b1.w;

        if (OUT_BF16) {
            unsigned short* out = (unsigned short*)out_;
            uint4 o;
            o.x = (unsigned int)f2bf(acc[0]) | ((unsigned int)f2bf(acc[1]) << 16);
            o.y = (unsigned int)f2bf(acc[2]) | ((unsigned int)f2bf(acc[3]) << 16);
            o.z = (unsigned int)f2bf(acc[4]) | ((unsigned int)f2bf(acc[5]) << 16);
            o.w = (unsigned int)f2bf(acc[6]) | ((unsigned int)f2bf(acc[7]) << 16);
            *(uint4*)(out + (size_t)node * DIM + j) = o;
        } else {
            float* out = (float*)out_;
            *(float4*)(out + (size_t)node * DIM + j)     = make_float4(acc[0], acc[1], acc[2], acc[3]);
            *(float4*)(out + (size_t)node * DIM + j + 4) = make_float4(acc[4], acc[5], acc[6], acc[7]);
        }
    }

    if constexpr (STATS) {
        // row padded to 257 floats: 4-way write conflicts max, reads ~free.
        __shared__ float red[16][257];
        #pragma unroll
        for (int k = 0; k < 8; ++k) {
            float a = valid ? acc[k] : 0.f;
            red[sub][j + k]       = a;
            red[sub][128 + j + k] = a * a;
        }
        __syncthreads();
        float t = 0.f;
        #pragma unroll
        for (int r = 0; r < 16; ++r) t += red[r][threadIdx.x];
        atomicAdd(&stat[(blockIdx.x & (STAT_COPIES - 1)) * 256 + threadIdx.x], t);
    }
}

// ---------------- BN finalize: fold stats into scale/shift ----------------

__global__ void bn_finalize_kernel(const float* __restrict__ stat,
                                   const float* __restrict__ gamma,
                                   const float* __restrict__ beta,
                                   float* __restrict__ mi, int n) {
    int c = threadIdx.x;
    if (c < DIM) {
        float s = 0.f, q = 0.f;
        #pragma unroll 4
        for (int cp = 0; cp < STAT_COPIES; ++cp) {
            s += stat[cp * 256 + c];
            q += stat[cp * 256 + 128 + c];
        }
        float mean  = s / (float)n;
        float var   = q / (float)n - mean * mean;
        float istd  = rsqrtf(var + BN_EPS);
        float scale = gamma[c] * istd;
        mi[c]       = scale;
        mi[DIM + c] = fmaf(-mean, scale, beta[c]);   // shift
    }
}

// ---------------- launch ----------------

extern "C" void kernel_launch(void* const* d_in, const int* in_sizes, int n_in,
                              void* d_out, int out_size, void* d_ws, size_t ws_size,
                              hipStream_t stream)
{
    const float* x      = (const float*)d_in[0];
    const int*   ei     = (const int*)  d_in[1];
    const float* W1     = (const float*)d_in[2];
    const float* b1     = (const float*)d_in[3];
    const float* gamma1 = (const float*)d_in[4];
    const float* beta1  = (const float*)d_in[5];
    const float* W2     = (const float*)d_in[6];
    const float* b2     = (const float*)d_in[7];
    float* out = (float*)d_out;

    const int N = in_sizes[0] / DIM;   // 100000
    const int E = in_sizes[1] / 2;     // 600000
    const int* row = ei;
    const int* col = ei + E;

    const int NB    = (N + 1023) / 1024;   // <= 256 (N <= 262144)
    const int degB  = (E + 255) / 256;
    const int scatB = (E + 511) / 512;     // 2 edges/thread
    const int gemmB = (N + 63) / 64;
    const int aggB  = (N + 15) / 16;
    // interleaved K4 grid: groups of 5 = 2 scatter + 3 gemm (matches block ratio)
    const int k4B   = 5 * max((scatB + 1) / 2, (gemmB + 2) / 3);

    // Workspace layout (8B-alignment-safe ordering). Zeroed region is contiguous:
    unsigned short* hw    = (unsigned short*)d_ws;         // N*128 bf16
    unsigned short* h1    = hw + (size_t)N * DIM;          // N*128 bf16
    int2*  epack  = (int2*)(h1 + (size_t)N * DIM);         // E (8B each)
    int2*  rp2    = epack + E;                             // N {start,end}
    unsigned short* wfrag = (unsigned short*)(rp2 + N);    // 2*16384 bf16
    float* dis    = (float*)(wfrag + 2 * 16384);           // N
    int*   rank   = (int*)(dis + N);                       // E (edge rank in bucket)
    int*   rowptr = rank + E;                              // N (scratch, per-block scan)
    int*   aux    = rowptr + N;                            // 256
    float* mi     = (float*)(aux + 256);                   // 256
    // ---- zeroed region start ----
    int*   deg    = (int*)(mi + 256);                      // N
    float* stat   = (float*)(deg + N);                     // 64*256
    const size_t zero_bytes = (size_t)N * 4 + (size_t)STAT_COPIES * 256 * 4;

    hipMemsetAsync(deg, 0, zero_bytes, stream);

    // K1: degree atomics (rank captured) + W conversion
    deg_convw_kernel<<<degB + 16, 256, 0, stream>>>(row, deg, rank, E, degB, W1, W2, wfrag);
    // K2: per-block exclusive scan (+ dis)
    scan_block_kernel<<<NB, 256, 0, stream>>>(deg, rowptr, aux, dis, N);
    // K3: cross-block offsets (self-computed aux prefix) -> rp2
    add_offsets_kernel<<<NB, 256, 0, stream>>>(rowptr, deg, aux, rp2, N);
    // K4: atomic-free scatter (2 edges/thread) interleaved (2:3 mod-5) with gemm1
    scatter_gemm1_kernel<<<k4B, 256, 0, stream>>>(row, col, rank, dis, rp2, epack, E, scatB,
                                                  x, wfrag, hw, N, gemmB);
    // K5: agg layer 1 + fused BN stats (spread atomics, no fence)
    agg_csr_kernel<true, true><<<aggB, 256, 0, stream>>>(hw, dis, rp2, epack, b1, h1, N,
                                                         stat);
    // K5b: fold stats -> BN scale/shift (1 tiny block; kernel boundary = coherence)
    bn_finalize_kernel<<<1, DIM, 0, stream>>>(stat, gamma1, beta1, mi, N);
    // K6: gemm2 with in-register BN(scale,shift)+ReLU, LDS-free
    gemm_mfma_bn_kernel<<<gemmB, 256, 0, stream>>>(h1, wfrag + 16384, hw, N, mi);
    // K7: agg layer 2 -> fp32 output
    agg_csr_kernel<false, false><<<aggB, 256, 0, stream>>>(hw, dis, rp2, epack, b2, out, N,
                                                           nullptr);
}

// Round 13
// 256.867 us; speedup vs baseline: 1.6061x; 1.0086x over previous
//
#include <hip/hip_runtime.h>

#define DIM 128
#define BN_EPS 1e-5f
#define STAT_COPIES 64

typedef short short8 __attribute__((ext_vector_type(8)));   // 8 bf16 bit patterns
typedef float floatx4 __attribute__((ext_vector_type(4)));

__device__ __forceinline__ unsigned short f2bf(float f) {
    unsigned int u = __builtin_bit_cast(unsigned int, f);
    u += 0x7FFFu + ((u >> 16) & 1u);          // RNE (inputs are finite)
    return (unsigned short)(u >> 16);
}
__device__ __forceinline__ float bf2f(unsigned short h) {
    return __builtin_bit_cast(float, (unsigned int)h << 16);
}

// ---------------- K1: degree (atomic, rank captured) + W->bf16 conversion ------
// rank[e] = edge's arrival index within its row bucket (free from atomicAdd
// return) -> scatter needs no second atomic pass.
// wfrag[((kt*8+nt)*64 + lane)*8 + j] = W[kt*32 + (lane>>4)*8 + j][nt*16 + (lane&15)]

__global__ __launch_bounds__(256) void deg_convw_kernel(
    const int* __restrict__ row, int* __restrict__ deg, int* __restrict__ rank,
    int E, int degB,
    const float* __restrict__ W1, const float* __restrict__ W2,
    unsigned short* __restrict__ wfrag)
{
    if ((int)blockIdx.x < degB) {
        int e = blockIdx.x * 256 + threadIdx.x;
        if (e < E) rank[e] = atomicAdd(&deg[row[e]], 1);
    } else {
        int s = (blockIdx.x - degB) * 256 + threadIdx.x;   // 0..4095
        if (s >= 4096) return;
        int m  = s >> 11;
        int s2 = s & 2047;
        int kt = s2 >> 9;
        int nt = (s2 >> 6) & 7;
        int l  = s2 & 63;
        const float* W = m ? W2 : W1;
        unsigned short* o = wfrag + (size_t)m * 16384 + (size_t)s2 * 8;
        int k0 = kt * 32 + (l >> 4) * 8;
        int n0 = nt * 16 + (l & 15);
        #pragma unroll
        for (int j = 0; j < 8; ++j) o[j] = f2bf(W[(k0 + j) * DIM + n0]);
    }
}

// ---------------- K2: per-block exclusive scan over deg (+ fused dis) ----------

__global__ __launch_bounds__(256) void scan_block_kernel(const int* __restrict__ deg,
                                                         int* __restrict__ rowptr,
                                                         int* __restrict__ aux,
                                                         float* __restrict__ dis, int n) {
    __shared__ int ls[256];
    const int base = blockIdx.x * 1024;
    const int t = threadIdx.x;
    int v[4]; int s = 0;
    #pragma unroll
    for (int k = 0; k < 4; ++k) {
        int i = base + t * 4 + k;
        v[k] = (i < n) ? deg[i] : 0;
        s += v[k];
    }
    ls[t] = s;
    __syncthreads();
    for (int off = 1; off < 256; off <<= 1) {
        int x = (t >= off) ? ls[t - off] : 0;
        __syncthreads();
        ls[t] += x;
        __syncthreads();
    }
    int excl = ls[t] - s;
    if (t == 255) aux[blockIdx.x] = ls[255];
    #pragma unroll
    for (int k = 0; k < 4; ++k) {
        int i = base + t * 4 + k;
        if (i < n) {
            rowptr[i] = excl;
            dis[i] = rsqrtf((float)(v[k] + 1));   // +1 self-loop; always > 0
        }
        excl += v[k];
    }
}

// ---------------- K3: add aux prefix (computed per-block), build rp2 ----------

__global__ __launch_bounds__(256) void add_offsets_kernel(
    const int* __restrict__ rowptr, const int* __restrict__ deg,
    const int* __restrict__ aux, int2* __restrict__ rp2, int n)
{
    __shared__ int red[256];
    const int t = threadIdx.x;
    red[t] = (t < (int)blockIdx.x) ? aux[t] : 0;   // blockIdx <= 255 by construction
    __syncthreads();
    for (int off = 128; off > 0; off >>= 1) {
        if (t < off) red[t] += red[t + off];
        __syncthreads();
    }
    const int base = red[0];
    #pragma unroll
    for (int k = 0; k < 4; ++k) {
        int i = blockIdx.x * 1024 + t * 4 + k;
        if (i < n) {
            int st = rowptr[i] + base;
            rp2[i] = make_int2(st, st + deg[i]);
        }
    }
}

// ---------------- K4a: standalone atomic-free scatter ----------------
// Round-13: un-merge from gemm1. Both halves were latency-bound; co-residency
// split the CU's wave slots without either side gaining (5 interleave variants
// all 42-46us). Standalone, scatter gets the full machine: pure loads + one
// random 8B store, pos = rp2[r].x + rank[e] (rank precomputed in K1).

__global__ __launch_bounds__(256) void scatter_kernel(
    const int* __restrict__ row, const int* __restrict__ col,
    const int* __restrict__ rank, const float* __restrict__ dis,
    const int2* __restrict__ rp2, int2* __restrict__ epack, int E)
{
    int e = blockIdx.x * 256 + threadIdx.x;
    if (e >= E) return;
    int r = row[e], c = col[e];
    int pos = rp2[r].x + rank[e];
    float nrm = dis[r] * dis[c];
    epack[pos] = make_int2(c, __builtin_bit_cast(int, nrm));
}

// ---------------- K4b: standalone MFMA GEMM layer 1 ----------------
// Direct fragment loads from global (A used once), no LDS, no barrier;
// r-outer/nt-inner store order.

__global__ __launch_bounds__(256) void gemm1_kernel(
    const float* __restrict__ A, const unsigned short* __restrict__ wfrag,
    unsigned short* __restrict__ C, int n)
{
    const int tid  = threadIdx.x;
    const int row0 = blockIdx.x * 64;
    const int wave = tid >> 6;
    const int lane = tid & 63;
    const int m    = lane & 15;
    const int quad = lane >> 4;
    const int rowA = row0 + wave * 16 + m;

    short8 af[4];
    if (rowA < n) {
        #pragma unroll
        for (int kt = 0; kt < 4; ++kt) {
            const float* src = A + (size_t)rowA * DIM + kt * 32 + quad * 8;
            float4 v0 = *(const float4*)(src);
            float4 v1 = *(const float4*)(src + 4);
            af[kt] = (short8){ (short)f2bf(v0.x), (short)f2bf(v0.y),
                               (short)f2bf(v0.z), (short)f2bf(v0.w),
                               (short)f2bf(v1.x), (short)f2bf(v1.y),
                               (short)f2bf(v1.z), (short)f2bf(v1.w) };
        }
    } else {
        #pragma unroll
        for (int kt = 0; kt < 4; ++kt) af[kt] = (short8){0,0,0,0,0,0,0,0};
    }

    floatx4 acc[8];
    #pragma unroll
    for (int nt = 0; nt < 8; ++nt) acc[nt] = (floatx4){0.f, 0.f, 0.f, 0.f};

    #pragma unroll
    for (int nt = 0; nt < 8; ++nt)
        #pragma unroll
        for (int kt = 0; kt < 4; ++kt) {
            short8 bfr = *(const short8*)(wfrag + ((size_t)(kt * 8 + nt) * 64 + lane) * 8);
            acc[nt] = __builtin_amdgcn_mfma_f32_16x16x32_bf16(af[kt], bfr, acc[nt], 0, 0, 0);
        }

    #pragma unroll
    for (int r = 0; r < 4; ++r) {
        int rr = row0 + wave * 16 + quad * 4 + r;
        if (rr < n) {
            #pragma unroll
            for (int nt = 0; nt < 8; ++nt)
                C[(size_t)rr * DIM + nt * 16 + m] = f2bf(acc[nt][r]);
        }
    }
}

// ---------------- K6: MFMA GEMM layer 2, direct bf16 fragment loads ------------
// BN scale/shift + ReLU applied in-register on the A fragment (verified path,
// round 6: absmax 0.03125). No LDS, no barrier.

__global__ __launch_bounds__(256) void gemm_mfma_bn_kernel(
    const unsigned short* __restrict__ Abf, const unsigned short* __restrict__ wfrag,
    unsigned short* __restrict__ C, int n,
    const float* __restrict__ mi)   // mi[0..127]=scale, mi[128..255]=shift
{
    const int tid  = threadIdx.x;
    const int row0 = blockIdx.x * 64;
    const int wave = tid >> 6;
    const int lane = tid & 63;
    const int m    = lane & 15;
    const int quad = lane >> 4;
    const int rowA = row0 + wave * 16 + m;

    short8 af[4];
    if (rowA < n) {
        #pragma unroll
        for (int kt = 0; kt < 4; ++kt) {
            const int c0 = kt * 32 + quad * 8;
            short8 v = *(const short8*)(Abf + (size_t)rowA * DIM + c0);
            float4 s0 = *(const float4*)(mi + c0);
            float4 s1 = *(const float4*)(mi + c0 + 4);
            float4 h0 = *(const float4*)(mi + 128 + c0);
            float4 h1 = *(const float4*)(mi + 128 + c0 + 4);
            float f[8];
            #pragma unroll
            for (int j = 0; j < 8; ++j) f[j] = bf2f((unsigned short)v[j]);
            f[0] = fmaxf(fmaf(f[0], s0.x, h0.x), 0.f);
            f[1] = fmaxf(fmaf(f[1], s0.y, h0.y), 0.f);
            f[2] = fmaxf(fmaf(f[2], s0.z, h0.z), 0.f);
            f[3] = fmaxf(fmaf(f[3], s0.w, h0.w), 0.f);
            f[4] = fmaxf(fmaf(f[4], s1.x, h1.x), 0.f);
            f[5] = fmaxf(fmaf(f[5], s1.y, h1.y), 0.f);
            f[6] = fmaxf(fmaf(f[6], s1.z, h1.z), 0.f);
            f[7] = fmaxf(fmaf(f[7], s1.w, h1.w), 0.f);
            af[kt] = (short8){ (short)f2bf(f[0]), (short)f2bf(f[1]),
                               (short)f2bf(f[2]), (short)f2bf(f[3]),
                               (short)f2bf(f[4]), (short)f2bf(f[5]),
                               (short)f2bf(f[6]), (short)f2bf(f[7]) };
        }
    } else {
        #pragma unroll
        for (int kt = 0; kt < 4; ++kt) af[kt] = (short8){0,0,0,0,0,0,0,0};
    }

    floatx4 acc[8];
    #pragma unroll
    for (int nt = 0; nt < 8; ++nt) acc[nt] = (floatx4){0.f, 0.f, 0.f, 0.f};

    #pragma unroll
    for (int nt = 0; nt < 8; ++nt)
        #pragma unroll
        for (int kt = 0; kt < 4; ++kt) {
            short8 bfr = *(const short8*)(wfrag + ((size_t)(kt * 8 + nt) * 64 + lane) * 8);
            acc[nt] = __builtin_amdgcn_mfma_f32_16x16x32_bf16(af[kt], bfr, acc[nt], 0, 0, 0);
        }

    #pragma unroll
    for (int r = 0; r < 4; ++r) {
        int rr = row0 + wave * 16 + quad * 4 + r;
        if (rr < n) {
            #pragma unroll
            for (int nt = 0; nt < 8; ++nt)
                C[(size_t)rr * DIM + nt * 16 + m] = f2bf(acc[nt][r]);
        }
    }
}

// ---------------- K5/K7: CSR aggregation ----------------
// 16 lanes/node, 8 ch/lane. out[i] = sum_e hw[col_e]*norm_e + hw[i]*dis_i^2 + bias.
// Uniform predicated unroll-8 loop: index clamped to pe-1, weight 0 for pad slots.
// STATS: LDS reduce + atomics over 64 spread copies. NO per-block threadfence
// (round-3 lesson: 6250x buffer_wbl2 serialized at the TCC = +620us).

__device__ __forceinline__ void acc8(float* acc, uint4 u, float w) {
    unsigned int a[4] = {u.x, u.y, u.z, u.w};
    #pragma unroll
    for (int k = 0; k < 4; ++k) {
        acc[2*k]   = fmaf(bf2f((unsigned short)(a[k] & 0xffff)), w, acc[2*k]);
        acc[2*k+1] = fmaf(bf2f((unsigned short)(a[k] >> 16)),    w, acc[2*k+1]);
    }
}

template <bool OUT_BF16, bool STATS>
__global__ __launch_bounds__(256) void agg_csr_kernel(
    const unsigned short* __restrict__ hw, const float* __restrict__ dis,
    const int2* __restrict__ rp2, const int2* __restrict__ epack,
    const float* __restrict__ bias, void* __restrict__ out_, int n,
    float* __restrict__ stat)
{
    const int sub  = threadIdx.x >> 4;        // 0..15 node slot in block
    const int l    = threadIdx.x & 15;
    const int node = blockIdx.x * 16 + sub;
    const bool valid = node < n;
    const int j = l * 8;

    float acc[8];
    #pragma unroll
    for (int k = 0; k < 8; ++k) acc[k] = 0.f;

    if (valid) {
        const int2 rp = rp2[node];            // one 8B load: {start, end}
        {   // self-loop term: hw[i] * dis_i^2
            const float d = dis[node];
            uint4 u = *(const uint4*)(hw + (size_t)node * DIM + j);
            acc8(acc, u, d * d);
        }

        const int pe = rp.y;
        for (int p = rp.x; p < pe; p += 8) {
            const int pm = pe - 1;
            int2 e[8];
            #pragma unroll
            for (int k = 0; k < 8; ++k) {
                int pk = p + k;
                e[k] = epack[pk < pm ? pk : pm];
            }
            uint4 u[8];
            #pragma unroll
            for (int k = 0; k < 8; ++k)
                u[k] = *(const uint4*)(hw + (size_t)e[k].x * DIM + j);
            #pragma unroll
            for (int k = 0; k < 8; ++k) {
                float w = (p + k < pe) ? __builtin_bit_cast(float, e[k].y) : 0.f;
                acc8(acc, u[k], w);
            }
        }

        float4 b0 = *(const float4*)(bias + j);
        float4 b1 = *(const float4*)(bias + j + 4);
        acc[0] += b0.x; acc[1] += b0.y; acc[2] += b0.z; acc[3] += b0.w;
        acc[4] += b1.x; acc[5] += b1.y; acc[6] += b1.z; acc[7] += b1.w;

        if (OUT_BF16) {
            unsigned short* out = (unsigned short*)out_;
            uint4 o;
            o.x = (unsigned int)f2bf(acc[0]) | ((unsigned int)f2bf(acc[1]) << 16);
            o.y = (unsigned int)f2bf(acc[2]) | ((unsigned int)f2bf(acc[3]) << 16);
            o.z = (unsigned int)f2bf(acc[4]) | ((unsigned int)f2bf(acc[5]) << 16);
            o.w = (unsigned int)f2bf(acc[6]) | ((unsigned int)f2bf(acc[7]) << 16);
            *(uint4*)(out + (size_t)node * DIM + j) = o;
        } else {
            float* out = (float*)out_;
            *(float4*)(out + (size_t)node * DIM + j)     = make_float4(acc[0], acc[1], acc[2], acc[3]);
            *(float4*)(out + (size_t)node * DIM + j + 4) = make_float4(acc[4], acc[5], acc[6], acc[7]);
        }
    }

    if constexpr (STATS) {
        // row padded to 257 floats: 4-way write conflicts max, reads ~free.
        __shared__ float red[16][257];
        #pragma unroll
        for (int k = 0; k < 8; ++k) {
            float a = valid ? acc[k] : 0.f;
            red[sub][j + k]       = a;
            red[sub][128 + j + k] = a * a;
        }
        __syncthreads();
        float t = 0.f;
        #pragma unroll
        for (int r = 0; r < 16; ++r) t += red[r][threadIdx.x];
        atomicAdd(&stat[(blockIdx.x & (STAT_COPIES - 1)) * 256 + threadIdx.x], t);
    }
}

// ---------------- BN finalize: fold stats into scale/shift ----------------

__global__ void bn_finalize_kernel(const float* __restrict__ stat,
                                   const float* __restrict__ gamma,
                                   const float* __restrict__ beta,
                                   float* __restrict__ mi, int n) {
    int c = threadIdx.x;
    if (c < DIM) {
        float s = 0.f, q = 0.f;
        #pragma unroll 4
        for (int cp = 0; cp < STAT_COPIES; ++cp) {
            s += stat[cp * 256 + c];
            q += stat[cp * 256 + 128 + c];
        }
        float mean  = s / (float)n;
        float var   = q / (float)n - mean * mean;
        float istd  = rsqrtf(var + BN_EPS);
        float scale = gamma[c] * istd;
        mi[c]       = scale;
        mi[DIM + c] = fmaf(-mean, scale, beta[c]);   // shift
    }
}

// ---------------- launch ----------------

extern "C" void kernel_launch(void* const* d_in, const int* in_sizes, int n_in,
                              void* d_out, int out_size, void* d_ws, size_t ws_size,
                              hipStream_t stream)
{
    const float* x      = (const float*)d_in[0];
    const int*   ei     = (const int*)  d_in[1];
    const float* W1     = (const float*)d_in[2];
    const float* b1     = (const float*)d_in[3];
    const float* gamma1 = (const float*)d_in[4];
    const float* beta1  = (const float*)d_in[5];
    const float* W2     = (const float*)d_in[6];
    const float* b2     = (const float*)d_in[7];
    float* out = (float*)d_out;

    const int N = in_sizes[0] / DIM;   // 100000
    const int E = in_sizes[1] / 2;     // 600000
    const int* row = ei;
    const int* col = ei + E;

    const int NB    = (N + 1023) / 1024;   // <= 256 (N <= 262144)
    const int degB  = (E + 255) / 256;
    const int gemmB = (N + 63) / 64;
    const int aggB  = (N + 15) / 16;

    // Workspace layout (8B-alignment-safe ordering). Zeroed region is contiguous:
    unsigned short* hw    = (unsigned short*)d_ws;         // N*128 bf16
    unsigned short* h1    = hw + (size_t)N * DIM;          // N*128 bf16
    int2*  epack  = (int2*)(h1 + (size_t)N * DIM);         // E (8B each)
    int2*  rp2    = epack + E;                             // N {start,end}
    unsigned short* wfrag = (unsigned short*)(rp2 + N);    // 2*16384 bf16
    float* dis    = (float*)(wfrag + 2 * 16384);           // N
    int*   rank   = (int*)(dis + N);                       // E (edge rank in bucket)
    int*   rowptr = rank + E;                              // N (scratch, per-block scan)
    int*   aux    = rowptr + N;                            // 256
    float* mi     = (float*)(aux + 256);                   // 256
    // ---- zeroed region start ----
    int*   deg    = (int*)(mi + 256);                      // N
    float* stat   = (float*)(deg + N);                     // 64*256
    const size_t zero_bytes = (size_t)N * 4 + (size_t)STAT_COPIES * 256 * 4;

    hipMemsetAsync(deg, 0, zero_bytes, stream);

    // K1: degree atomics (rank captured) + W conversion
    deg_convw_kernel<<<degB + 16, 256, 0, stream>>>(row, deg, rank, E, degB, W1, W2, wfrag);
    // K2: per-block exclusive scan (+ dis)
    scan_block_kernel<<<NB, 256, 0, stream>>>(deg, rowptr, aux, dis, N);
    // K3: cross-block offsets (self-computed aux prefix) -> rp2
    add_offsets_kernel<<<NB, 256, 0, stream>>>(rowptr, deg, aux, rp2, N);
    // K4a: standalone atomic-free scatter (full machine, pure loads + 8B store)
    scatter_kernel<<<degB, 256, 0, stream>>>(row, col, rank, dis, rp2, epack, E);
    // K4b: standalone gemm1 (direct fragment loads, no LDS)
    gemm1_kernel<<<gemmB, 256, 0, stream>>>(x, wfrag, hw, N);
    // K5: agg layer 1 + fused BN stats (spread atomics, no fence)
    agg_csr_kernel<true, true><<<aggB, 256, 0, stream>>>(hw, dis, rp2, epack, b1, h1, N,
                                                         stat);
    // K5b: fold stats -> BN scale/shift (1 tiny block; kernel boundary = coherence)
    bn_finalize_kernel<<<1, DIM, 0, stream>>>(stat, gamma1, beta1, mi, N);
    // K6: gemm2 with in-register BN(scale,shift)+ReLU, LDS-free
    gemm_mfma_bn_kernel<<<gemmB, 256, 0, stream>>>(h1, wfrag + 16384, hw, N, mi);
    // K7: agg layer 2 -> fp32 output
    agg_csr_kernel<false, false><<<aggB, 256, 0, stream>>>(hw, dis, rp2, epack, b2, out, N,
                                                           nullptr);
}